// Round 1
// baseline (2095.789 us; speedup 1.0000x reference)
//
#include <hip/hip_runtime.h>
#include <hip/hip_bf16.h>
#include <math.h>

// Problem constants (from reference)
#define N_NODES 2048
#define C_NODES 256
#define BATCH   64
#define UNITS   64
#define FDIM    65                 // INPUT_DIM + NUM_UNITS = 1 + 64
#define FB      (BATCH * FDIM)     // 4160 columns, layout j = b*FDIM + f
#define NU      (N_NODES * UNITS)  // 131072

__device__ __forceinline__ float sigmoidf_(float x) {
    return 1.0f / (1.0f + __expf(-x));
}

// Build x0 (N_NODES x FB): x0[n, b*F+0] = inputs[b,n]; x0[n, b*F+1+u] = state[b, n*64+u]
__global__ __launch_bounds__(256) void build_x0_kernel(
    const float* __restrict__ inputs, const float* __restrict__ state,
    float* __restrict__ x0)
{
    int n = blockIdx.x;
    for (int j = threadIdx.x; j < FB; j += 256) {
        int b = j / FDIM;
        int f = j - b * FDIM;
        float v;
        if (f == 0) v = inputs[(size_t)b * N_NODES + n];
        else        v = state[(size_t)b * NU + (size_t)n * UNITS + (f - 1)];
        x0[(size_t)n * FB + j] = v;
    }
}

// Tiled fp32 GEMM: Out[M,J] = A[M,K] @ X[K,J]
// EPI==0: plain store. EPI==1: Out += sigmoid(acc)  (Out pre-holds the additive term)
// Requires M%64==0, J%64==0, K%16==0.
template <int EPI>
__global__ __launch_bounds__(256) void gemm_f32(
    const float* __restrict__ A, const float* __restrict__ X,
    float* __restrict__ Out, int M, int K, int J)
{
    __shared__ float As[16 * 65];  // padded stride 65 to avoid bank conflicts
    __shared__ float Xs[16 * 64];

    int tid = threadIdx.x;
    int tx = tid & 15;          // 0..15 -> 4 cols each
    int ty = tid >> 4;          // 0..15 -> 4 rows each
    int jBase = blockIdx.x * 64;
    int mBase = blockIdx.y * 64;

    float acc[4][4] = {};

    for (int k0 = 0; k0 < K; k0 += 16) {
        #pragma unroll
        for (int i = 0; i < 4; i++) {
            int idx = tid + i * 256;        // 0..1023
            int m  = idx >> 4;              // 0..63
            int kk = idx & 15;              // 0..15
            As[kk * 65 + m] = A[(size_t)(mBase + m) * K + (k0 + kk)];
        }
        #pragma unroll
        for (int i = 0; i < 4; i++) {
            int idx = tid + i * 256;
            int kk = idx >> 6;              // 0..15
            int j  = idx & 63;              // 0..63
            Xs[kk * 64 + j] = X[(size_t)(k0 + kk) * J + (jBase + j)];
        }
        __syncthreads();

        #pragma unroll
        for (int kk = 0; kk < 16; kk++) {
            float a0 = As[kk * 65 + ty * 4 + 0];
            float a1 = As[kk * 65 + ty * 4 + 1];
            float a2 = As[kk * 65 + ty * 4 + 2];
            float a3 = As[kk * 65 + ty * 4 + 3];
            float4 xv = *(const float4*)&Xs[kk * 64 + tx * 4];
            acc[0][0] += a0 * xv.x; acc[0][1] += a0 * xv.y; acc[0][2] += a0 * xv.z; acc[0][3] += a0 * xv.w;
            acc[1][0] += a1 * xv.x; acc[1][1] += a1 * xv.y; acc[1][2] += a1 * xv.z; acc[1][3] += a1 * xv.w;
            acc[2][0] += a2 * xv.x; acc[2][1] += a2 * xv.y; acc[2][2] += a2 * xv.z; acc[2][3] += a2 * xv.w;
            acc[3][0] += a3 * xv.x; acc[3][1] += a3 * xv.y; acc[3][2] += a3 * xv.z; acc[3][3] += a3 * xv.w;
        }
        __syncthreads();
    }

    #pragma unroll
    for (int i = 0; i < 4; i++) {
        int m = mBase + ty * 4 + i;
        #pragma unroll
        for (int jj = 0; jj < 4; jj++) {
            int c = jBase + tx * 4 + jj;
            size_t idx = (size_t)m * J + c;
            if (EPI == 0) Out[idx] = acc[i][jj];
            else          Out[idx] = Out[idx] + sigmoidf_(acc[i][jj]);
        }
    }
}

// head1: per node n, out1[b,o] = sum_f x1[n, b*F+f] * w0[f,o] + b0[o], o in [0,128)
//   r = sigmoid(out1[:, :64])  -> x0[n, b*F+1+u] = r * state[b, n*64+u]   (in-place new x0)
//   u = sigmoid(out1[:, 64:])  -> u_buf[(n*64+b)*64 + u]
__global__ __launch_bounds__(256) void head1_kernel(
    const float* __restrict__ x1, const float* __restrict__ w0,
    const float* __restrict__ b0, const float* __restrict__ state,
    float* __restrict__ x0, float* __restrict__ u_buf)
{
    __shared__ float Xs[FB];           // 4160 floats
    __shared__ float Ws[FDIM * 128];   // 8320 floats

    int n = blockIdx.x;
    for (int j = threadIdx.x; j < FB; j += 256) Xs[j] = x1[(size_t)n * FB + j];
    for (int j = threadIdx.x; j < FDIM * 128; j += 256) Ws[j] = w0[j];
    __syncthreads();

    int t = threadIdx.x;
    int b = t >> 2;                 // 0..63
    int obase = (t & 3) * 32;       // 0,32,64,96

    float acc[32];
    #pragma unroll
    for (int i = 0; i < 32; i++) acc[i] = b0[obase + i];

    for (int f = 0; f < FDIM; f++) {
        float xv = Xs[b * FDIM + f];
        const float* wrow = &Ws[f * 128 + obase];
        #pragma unroll
        for (int i = 0; i < 32; i++) acc[i] += xv * wrow[i];
    }

    if (obase < 64) {
        // r part
        #pragma unroll
        for (int i = 0; i < 32; i++) {
            int o = obase + i;
            float val = sigmoidf_(acc[i]);
            float sv = state[(size_t)b * NU + (size_t)n * UNITS + o];
            x0[(size_t)n * FB + b * FDIM + 1 + o] = val * sv;
        }
    } else {
        // u part
        #pragma unroll
        for (int i = 0; i < 32; i++) {
            int o = obase + i;
            float val = sigmoidf_(acc[i]);
            u_buf[((size_t)n * 64 + b) * 64 + (o - 64)] = val;
        }
    }
}

// head2: per node n, out2[b,u] = sum_f x1[n, b*F+f] * w1[f,u] + b1[u], u in [0,64)
//   c = tanh(out2); new_state[b, n*64+u] = u_g * state + (1-u_g) * c
__global__ __launch_bounds__(256) void head2_kernel(
    const float* __restrict__ x1, const float* __restrict__ w1,
    const float* __restrict__ b1, const float* __restrict__ state,
    const float* __restrict__ u_buf, float* __restrict__ out)
{
    __shared__ float Xs[FB];          // 4160
    __shared__ float Ws[FDIM * 64];   // 4160

    int n = blockIdx.x;
    for (int j = threadIdx.x; j < FB; j += 256) Xs[j] = x1[(size_t)n * FB + j];
    for (int j = threadIdx.x; j < FDIM * 64; j += 256) Ws[j] = w1[j];
    __syncthreads();

    int t = threadIdx.x;
    int b = t >> 2;                 // 0..63
    int obase = (t & 3) * 16;       // 0,16,32,48

    float acc[16];
    #pragma unroll
    for (int i = 0; i < 16; i++) acc[i] = b1[obase + i];

    for (int f = 0; f < FDIM; f++) {
        float xv = Xs[b * FDIM + f];
        const float* wrow = &Ws[f * 64 + obase];
        #pragma unroll
        for (int i = 0; i < 16; i++) acc[i] += xv * wrow[i];
    }

    #pragma unroll
    for (int i = 0; i < 16; i++) {
        int uu = obase + i;
        float c = tanhf(acc[i]);
        float ug = u_buf[((size_t)n * 64 + b) * 64 + uu];
        size_t sidx = (size_t)b * NU + (size_t)n * UNITS + uu;
        float sv = state[sidx];
        out[sidx] = ug * sv + (1.0f - ug) * c;
    }
}

extern "C" void kernel_launch(void* const* d_in, const int* in_sizes, int n_in,
                              void* d_out, int out_size, void* d_ws, size_t ws_size,
                              hipStream_t stream)
{
    const float* inputs = (const float*)d_in[0];
    const float* state  = (const float*)d_in[1];
    const float* adj    = (const float*)d_in[2];
    // d_in[3] = adj1  : unused (feeds only the discarded outfc path)
    const float* afc    = (const float*)d_in[4];
    const float* afct   = (const float*)d_in[5];
    const float* w0     = (const float*)d_in[6];
    const float* b0     = (const float*)d_in[7];
    const float* w1     = (const float*)d_in[8];
    const float* b1     = (const float*)d_in[9];
    // d_in[10..13] = w01,b01,w11,b11 : unused (discarded outfc path)

    float* out = (float*)d_out;
    float* ws  = (float*)d_ws;

    float* x0    = ws;                                  // 2048*4160   = 8,519,680 f
    float* x0fc  = x0   + (size_t)N_NODES * FB;         // 256*4160    = 1,064,960 f
    float* x1    = x0fc + (size_t)C_NODES * FB;         // 2048*4160   = 8,519,680 f
    float* u_buf = x1   + (size_t)N_NODES * FB;         // 2048*64*64  = 8,388,608 f
    // total ~106 MB

    dim3 blk(256);
    dim3 gFull(FB / 64, N_NODES / 64);   // 65 x 32
    dim3 gCoar(FB / 64, C_NODES / 64);   // 65 x 4

    // ---- pass 1 (state) ----
    build_x0_kernel<<<N_NODES, blk, 0, stream>>>(inputs, state, x0);
    gemm_f32<0><<<gCoar, blk, 0, stream>>>(afc,  x0,   x0fc, C_NODES, N_NODES, FB);
    gemm_f32<0><<<gFull, blk, 0, stream>>>(adj,  x0,   x1,   N_NODES, N_NODES, FB);
    gemm_f32<1><<<gFull, blk, 0, stream>>>(afct, x0fc, x1,   N_NODES, C_NODES, FB);
    head1_kernel<<<N_NODES, blk, 0, stream>>>(x1, w0, b0, state, x0, u_buf);

    // ---- pass 2 (r*state), x0 state-columns updated in place by head1 ----
    gemm_f32<0><<<gCoar, blk, 0, stream>>>(afc,  x0,   x0fc, C_NODES, N_NODES, FB);
    gemm_f32<0><<<gFull, blk, 0, stream>>>(adj,  x0,   x1,   N_NODES, N_NODES, FB);
    gemm_f32<1><<<gFull, blk, 0, stream>>>(afct, x0fc, x1,   N_NODES, C_NODES, FB);
    head2_kernel<<<N_NODES, blk, 0, stream>>>(x1, w1, b1, state, u_buf, out);
}

// Round 3
// 876.579 us; speedup vs baseline: 2.3909x; 2.3909x over previous
//
#include <hip/hip_runtime.h>
#include <hip/hip_bf16.h>
#include <math.h>

#define N_NODES 2048
#define C_NODES 256
#define BATCH   64
#define UNITS   64
#define FDIM    65                  // 1 + 64
#define FB      4160                // BATCH * FDIM
#define JPAD    4224                // 33 * 128
#define NU      131072              // N_NODES * UNITS

typedef short  s16x8 __attribute__((ext_vector_type(8)));   // 8 bf16 in 4 VGPRs
typedef float  f32x4 __attribute__((ext_vector_type(4)));

__device__ __forceinline__ float sigmoidf_(float x) { return 1.0f / (1.0f + __expf(-x)); }

__device__ __forceinline__ void gload_lds16(const void* g, void* l) {
    __builtin_amdgcn_global_load_lds(
        (const __attribute__((address_space(1))) void*)g,
        (__attribute__((address_space(3))) void*)l, 16, 0, 0);
}

// ---- fp32 -> bf16 (plain, for adj) ----
__global__ __launch_bounds__(256) void cvt_bf16(const float* __restrict__ s,
                                                __hip_bfloat16* __restrict__ d, int n)
{
    int stride = gridDim.x * 256;
    for (int i = blockIdx.x * 256 + threadIdx.x; i < n; i += stride)
        d[i] = __float2bfloat16(s[i]);
}

// ---- fp32 -> hi/lo bf16 pair (for the precision-critical coarse-path matrices) ----
__global__ __launch_bounds__(256) void cvt_split(const float* __restrict__ s,
                                                 __hip_bfloat16* __restrict__ dh,
                                                 __hip_bfloat16* __restrict__ dl, int n)
{
    int stride = gridDim.x * 256;
    for (int i = blockIdx.x * 256 + threadIdx.x; i < n; i += stride) {
        float v = s[i];
        __hip_bfloat16 h = __float2bfloat16(v);
        dh[i] = h;
        dl[i] = __float2bfloat16(v - __bfloat162float(h));
    }
}

// ---- build x0T[j = b*65+f][n] hi/lo from inputs (f=0) and fp32 state-layout array ----
__global__ __launch_bounds__(256) void build_x0T_kernel(
    const float* __restrict__ inputs, const float* __restrict__ st,
    __hip_bfloat16* __restrict__ xh, __hip_bfloat16* __restrict__ xl)
{
    __shared__ float Ls[64 * 65];
    int n0 = blockIdx.x * 64;
    int b  = blockIdx.y;
    int t  = threadIdx.x;
    #pragma unroll
    for (int it = 0; it < 16; it++) {
        int idx = t + it * 256;
        int i = idx >> 6, u = idx & 63;           // read coalesced in u
        Ls[i * 65 + u] = st[(size_t)b * NU + (size_t)(n0 + i) * 64 + u];
    }
    __syncthreads();
    #pragma unroll
    for (int it = 0; it < 16; it++) {
        int idx = t + it * 256;
        int u = idx >> 6, i = idx & 63;           // write coalesced in n
        float v = Ls[i * 65 + u];
        __hip_bfloat16 h = __float2bfloat16(v);
        size_t o = (size_t)(b * FDIM + 1 + u) * N_NODES + n0 + i;
        xh[o] = h;
        xl[o] = __float2bfloat16(v - __bfloat162float(h));
    }
    if (t < 64) {
        float v = inputs[(size_t)b * N_NODES + n0 + t];
        __hip_bfloat16 h = __float2bfloat16(v);
        size_t o = (size_t)(b * FDIM) * N_NODES + n0 + t;
        xh[o] = h;
        xl[o] = __float2bfloat16(v - __bfloat162float(h));
    }
}

// ---- plain bf16 MFMA GEMM: OutF[M][N] = A[M][K] @ Bt[N][K]^T (fp32 store) ----
// 128x128 tile, 4 waves x (64x64 = 4x4 mfma_16x16x32), BK=64, global_load_lds w=16.
__global__ __launch_bounds__(256, 2) void gemm_mfma(
    const __hip_bfloat16* __restrict__ A,
    const __hip_bfloat16* __restrict__ Bt,
    float* __restrict__ OutF, int M, int K, int N, int ldOut)
{
    __shared__ __align__(16) __hip_bfloat16 As[8192];  // 16 KB
    __shared__ __align__(16) __hip_bfloat16 Bs[8192];  // 16 KB

    int tid  = threadIdx.x;
    int wave = tid >> 6, lane = tid & 63;
    int quad = lane >> 4, lr = lane & 15;
    int wr = wave >> 1, wc = wave & 1;
    int mBase = blockIdx.y * 128, nBase = blockIdx.x * 128;

    const __hip_bfloat16* gA[4]; const __hip_bfloat16* gB[4];
    __hip_bfloat16* lA[4]; __hip_bfloat16* lB[4];
    #pragma unroll
    for (int ch = 0; ch < 4; ch++) {
        int cell = (wave * 4 + ch) * 64 + lane;
        int kb = cell >> 7, mm = cell & 127;
        gA[ch] = A  + (size_t)(mBase + mm) * K + kb * 8;
        gB[ch] = Bt + (size_t)(nBase + mm) * K + kb * 8;
        lA[ch] = As + (wave * 4 + ch) * 512;
        lB[ch] = Bs + (wave * 4 + ch) * 512;
    }

    f32x4 acc[4][4];
    #pragma unroll
    for (int i = 0; i < 4; i++)
        #pragma unroll
        for (int j = 0; j < 4; j++) { f32x4 z = {0.f,0.f,0.f,0.f}; acc[i][j] = z; }

    for (int k0 = 0; k0 < K; k0 += 64) {
        #pragma unroll
        for (int ch = 0; ch < 4; ch++) {
            gload_lds16(gA[ch] + k0, lA[ch]);
            gload_lds16(gB[ch] + k0, lB[ch]);
        }
        __syncthreads();
        const s16x8* AsV = (const s16x8*)As;
        const s16x8* BsV = (const s16x8*)Bs;
        #pragma unroll
        for (int ks = 0; ks < 2; ks++) {
            int kb = ks * 4 + quad;
            s16x8 af[4], bfr[4];
            #pragma unroll
            for (int i = 0; i < 4; i++) af[i]  = AsV[kb * 128 + wr * 64 + i * 16 + lr];
            #pragma unroll
            for (int j = 0; j < 4; j++) bfr[j] = BsV[kb * 128 + wc * 64 + j * 16 + lr];
            #pragma unroll
            for (int i = 0; i < 4; i++)
                #pragma unroll
                for (int j = 0; j < 4; j++)
                    acc[i][j] = __builtin_amdgcn_mfma_f32_16x16x32_bf16(af[i], bfr[j], acc[i][j], 0, 0, 0);
        }
        __syncthreads();
    }

    #pragma unroll
    for (int i = 0; i < 4; i++)
        #pragma unroll
        for (int j = 0; j < 4; j++)
            #pragma unroll
            for (int r = 0; r < 4; r++) {
                int row = mBase + wr * 64 + i * 16 + quad * 4 + r;
                int col = nBase + wc * 64 + j * 16 + lr;
                OutF[(size_t)row * ldOut + col] = acc[i][j][r];
            }
}

// ---- split bf16 MFMA GEMM: acc = Ah·Bh + Ah·Bl + Al·Bh  (~fp32 product precision) ----
// EPI==1: store hi/lo bf16 pair. EPI==2: OutF += sigmoid(acc).
template<int EPI>
__global__ __launch_bounds__(256, 2) void gemm_mfma_split(
    const __hip_bfloat16* __restrict__ Ah, const __hip_bfloat16* __restrict__ Al,
    const __hip_bfloat16* __restrict__ Bh, const __hip_bfloat16* __restrict__ Bl,
    float* __restrict__ OutF, __hip_bfloat16* __restrict__ OutHi, __hip_bfloat16* __restrict__ OutLo,
    int M, int K, int N, int ldOut)
{
    __shared__ __align__(16) __hip_bfloat16 Ash[8192];
    __shared__ __align__(16) __hip_bfloat16 Asl[8192];
    __shared__ __align__(16) __hip_bfloat16 Bsh[8192];
    __shared__ __align__(16) __hip_bfloat16 Bsl[8192];   // 64 KB total

    int tid  = threadIdx.x;
    int wave = tid >> 6, lane = tid & 63;
    int quad = lane >> 4, lr = lane & 15;
    int wr = wave >> 1, wc = wave & 1;
    int mBase = blockIdx.y * 128, nBase = blockIdx.x * 128;

    const __hip_bfloat16 *gAh[4], *gAl[4], *gBh[4], *gBl[4];
    __hip_bfloat16 *lAh[4], *lAl[4], *lBh[4], *lBl[4];
    #pragma unroll
    for (int ch = 0; ch < 4; ch++) {
        int cell = (wave * 4 + ch) * 64 + lane;
        int kb = cell >> 7, mm = cell & 127;
        size_t offA = (size_t)(mBase + mm) * K + kb * 8;
        size_t offB = (size_t)(nBase + mm) * K + kb * 8;
        gAh[ch] = Ah + offA; gAl[ch] = Al + offA;
        gBh[ch] = Bh + offB; gBl[ch] = Bl + offB;
        int lo = (wave * 4 + ch) * 512;
        lAh[ch] = Ash + lo; lAl[ch] = Asl + lo;
        lBh[ch] = Bsh + lo; lBl[ch] = Bsl + lo;
    }

    f32x4 acc[4][4];
    #pragma unroll
    for (int i = 0; i < 4; i++)
        #pragma unroll
        for (int j = 0; j < 4; j++) { f32x4 z = {0.f,0.f,0.f,0.f}; acc[i][j] = z; }

    for (int k0 = 0; k0 < K; k0 += 64) {
        #pragma unroll
        for (int ch = 0; ch < 4; ch++) {
            gload_lds16(gAh[ch] + k0, lAh[ch]);
            gload_lds16(gAl[ch] + k0, lAl[ch]);
            gload_lds16(gBh[ch] + k0, lBh[ch]);
            gload_lds16(gBl[ch] + k0, lBl[ch]);
        }
        __syncthreads();
        const s16x8* AhV = (const s16x8*)Ash;
        const s16x8* AlV = (const s16x8*)Asl;
        const s16x8* BhV = (const s16x8*)Bsh;
        const s16x8* BlV = (const s16x8*)Bsl;
        #pragma unroll
        for (int ks = 0; ks < 2; ks++) {
            int kb = ks * 4 + quad;
            s16x8 ah[4], al[4], bh[4], bl[4];
            #pragma unroll
            for (int i = 0; i < 4; i++) {
                int idx = kb * 128 + wr * 64 + i * 16 + lr;
                ah[i] = AhV[idx]; al[i] = AlV[idx];
            }
            #pragma unroll
            for (int j = 0; j < 4; j++) {
                int idx = kb * 128 + wc * 64 + j * 16 + lr;
                bh[j] = BhV[idx]; bl[j] = BlV[idx];
            }
            #pragma unroll
            for (int i = 0; i < 4; i++)
                #pragma unroll
                for (int j = 0; j < 4; j++) {
                    acc[i][j] = __builtin_amdgcn_mfma_f32_16x16x32_bf16(ah[i], bh[j], acc[i][j], 0, 0, 0);
                    acc[i][j] = __builtin_amdgcn_mfma_f32_16x16x32_bf16(ah[i], bl[j], acc[i][j], 0, 0, 0);
                    acc[i][j] = __builtin_amdgcn_mfma_f32_16x16x32_bf16(al[i], bh[j], acc[i][j], 0, 0, 0);
                }
        }
        __syncthreads();
    }

    #pragma unroll
    for (int i = 0; i < 4; i++)
        #pragma unroll
        for (int j = 0; j < 4; j++)
            #pragma unroll
            for (int r = 0; r < 4; r++) {
                int row = mBase + wr * 64 + i * 16 + quad * 4 + r;
                int col = nBase + wc * 64 + j * 16 + lr;
                float v = acc[i][j][r];
                size_t idx = (size_t)row * ldOut + col;
                if (EPI == 1) {
                    __hip_bfloat16 h = __float2bfloat16(v);
                    OutHi[idx] = h;
                    OutLo[idx] = __float2bfloat16(v - __bfloat162float(h));
                } else {
                    OutF[idx] = OutF[idx] + sigmoidf_(v);
                }
            }
}

// ---- head1: r,u gates; rs = r*state (fp32, state layout), u_buf (bf16) ----
__global__ __launch_bounds__(256) void head1_kernel(
    const float* __restrict__ x1, const float* __restrict__ w0,
    const float* __restrict__ b0, const float* __restrict__ state,
    float* __restrict__ rs, __hip_bfloat16* __restrict__ u_buf)
{
    __shared__ float Xs[FB];
    __shared__ float Ws[FDIM * 128];
    int n = blockIdx.x;
    for (int j = threadIdx.x; j < FB; j += 256) Xs[j] = x1[(size_t)n * JPAD + j];
    for (int j = threadIdx.x; j < FDIM * 128; j += 256) Ws[j] = w0[j];
    __syncthreads();

    int t = threadIdx.x;
    int b = t >> 2;
    int obase = (t & 3) * 32;

    float acc[32];
    #pragma unroll
    for (int i = 0; i < 32; i++) acc[i] = b0[obase + i];
    for (int f = 0; f < FDIM; f++) {
        float xv = Xs[b * FDIM + f];
        const float* wrow = &Ws[f * 128 + obase];
        #pragma unroll
        for (int i = 0; i < 32; i++) acc[i] += xv * wrow[i];
    }

    if (obase < 64) {
        #pragma unroll
        for (int i = 0; i < 32; i++) {
            int o = obase + i;
            float val = sigmoidf_(acc[i]);
            float sv = state[(size_t)b * NU + (size_t)n * UNITS + o];
            rs[(size_t)b * NU + (size_t)n * UNITS + o] = val * sv;
        }
    } else {
        #pragma unroll
        for (int i = 0; i < 32; i++) {
            int o = obase + i - 64;
            u_buf[((size_t)n * 64 + b) * 64 + o] = __float2bfloat16(sigmoidf_(acc[i]));
        }
    }
}

// ---- head2: c = tanh(head); out = u*state + (1-u)*c ----
__global__ __launch_bounds__(256) void head2_kernel(
    const float* __restrict__ x1, const float* __restrict__ w1,
    const float* __restrict__ b1, const float* __restrict__ state,
    const __hip_bfloat16* __restrict__ u_buf, float* __restrict__ out)
{
    __shared__ float Xs[FB];
    __shared__ float Ws[FDIM * 64];
    int n = blockIdx.x;
    for (int j = threadIdx.x; j < FB; j += 256) Xs[j] = x1[(size_t)n * JPAD + j];
    for (int j = threadIdx.x; j < FDIM * 64; j += 256) Ws[j] = w1[j];
    __syncthreads();

    int t = threadIdx.x;
    int b = t >> 2;
    int obase = (t & 3) * 16;

    float acc[16];
    #pragma unroll
    for (int i = 0; i < 16; i++) acc[i] = b1[obase + i];
    for (int f = 0; f < FDIM; f++) {
        float xv = Xs[b * FDIM + f];
        const float* wrow = &Ws[f * 64 + obase];
        #pragma unroll
        for (int i = 0; i < 16; i++) acc[i] += xv * wrow[i];
    }

    #pragma unroll
    for (int i = 0; i < 16; i++) {
        int uu = obase + i;
        float c = tanhf(acc[i]);
        float ug = __bfloat162float(u_buf[((size_t)n * 64 + b) * 64 + uu]);
        size_t sidx = (size_t)b * NU + (size_t)n * UNITS + uu;
        float sv = state[sidx];
        out[sidx] = ug * sv + (1.0f - ug) * c;
    }
}

extern "C" void kernel_launch(void* const* d_in, const int* in_sizes, int n_in,
                              void* d_out, int out_size, void* d_ws, size_t ws_size,
                              hipStream_t stream)
{
    const float* inputs = (const float*)d_in[0];
    const float* state  = (const float*)d_in[1];
    const float* adj    = (const float*)d_in[2];
    // d_in[3] = adj1 : unused (discarded outfc path)
    const float* afc    = (const float*)d_in[4];   // [C][N]
    const float* afct   = (const float*)d_in[5];   // [N][C]
    const float* w0     = (const float*)d_in[6];
    const float* b0     = (const float*)d_in[7];
    const float* w1     = (const float*)d_in[8];
    const float* b1     = (const float*)d_in[9];
    // d_in[10..13]: unused

    float* out = (float*)d_out;

    char* p = (char*)d_ws;
    __hip_bfloat16* adj_b   = (__hip_bfloat16*)p; p += (size_t)N_NODES * N_NODES * 2;   // 8.4 MB
    __hip_bfloat16* afc_h   = (__hip_bfloat16*)p; p += (size_t)C_NODES * N_NODES * 2;   // 1.05
    __hip_bfloat16* afc_l   = (__hip_bfloat16*)p; p += (size_t)C_NODES * N_NODES * 2;   // 1.05
    __hip_bfloat16* afct_h  = (__hip_bfloat16*)p; p += (size_t)N_NODES * C_NODES * 2;   // 1.05
    __hip_bfloat16* afct_l  = (__hip_bfloat16*)p; p += (size_t)N_NODES * C_NODES * 2;   // 1.05
    __hip_bfloat16* x0T_h   = (__hip_bfloat16*)p; p += (size_t)JPAD * N_NODES * 2;      // 17.3
    __hip_bfloat16* x0T_l   = (__hip_bfloat16*)p; p += (size_t)JPAD * N_NODES * 2;      // 17.3
    __hip_bfloat16* x0fcT_h = (__hip_bfloat16*)p; p += (size_t)JPAD * C_NODES * 2;      // 2.2
    __hip_bfloat16* x0fcT_l = (__hip_bfloat16*)p; p += (size_t)JPAD * C_NODES * 2;      // 2.2
    float*          x1      = (float*)p;          p += (size_t)N_NODES * JPAD * 4;      // 34.6
    __hip_bfloat16* u_buf   = (__hip_bfloat16*)p; p += (size_t)N_NODES * BATCH * 64 * 2;// 16.8
    float*          rs      = (float*)p;          p += (size_t)BATCH * NU * 4;          // 33.5
    // total ~136.5 MB

    dim3 blk(256);
    dim3 gT(32, 64);                        // build_x0T
    dim3 g1(C_NODES / 128, JPAD / 128);     // (2, 33)   coarse GEMM1
    dim3 g2(JPAD / 128, N_NODES / 128);     // (33, 16)  adj GEMM / coarse GEMM2

    cvt_bf16 <<<1024, blk, 0, stream>>>(adj,  adj_b, N_NODES * N_NODES);
    cvt_split<<<256,  blk, 0, stream>>>(afc,  afc_h,  afc_l,  C_NODES * N_NODES);
    cvt_split<<<256,  blk, 0, stream>>>(afct, afct_h, afct_l, N_NODES * C_NODES);

    // ---- pass 1 ----
    build_x0T_kernel<<<gT, blk, 0, stream>>>(inputs, state, x0T_h, x0T_l);
    gemm_mfma_split<1><<<g1, blk, 0, stream>>>(x0T_h, x0T_l, afc_h, afc_l,
                                               nullptr, x0fcT_h, x0fcT_l,
                                               JPAD, N_NODES, C_NODES, C_NODES);
    gemm_mfma<<<g2, blk, 0, stream>>>(adj_b, x0T_h, x1, N_NODES, N_NODES, JPAD, JPAD);
    gemm_mfma_split<2><<<g2, blk, 0, stream>>>(afct_h, afct_l, x0fcT_h, x0fcT_l,
                                               x1, nullptr, nullptr,
                                               N_NODES, C_NODES, JPAD, JPAD);
    head1_kernel<<<N_NODES, blk, 0, stream>>>(x1, w0, b0, state, rs, u_buf);

    // ---- pass 2 (state' = r*state, fp32) ----
    build_x0T_kernel<<<gT, blk, 0, stream>>>(inputs, rs, x0T_h, x0T_l);
    gemm_mfma_split<1><<<g1, blk, 0, stream>>>(x0T_h, x0T_l, afc_h, afc_l,
                                               nullptr, x0fcT_h, x0fcT_l,
                                               JPAD, N_NODES, C_NODES, C_NODES);
    gemm_mfma<<<g2, blk, 0, stream>>>(adj_b, x0T_h, x1, N_NODES, N_NODES, JPAD, JPAD);
    gemm_mfma_split<2><<<g2, blk, 0, stream>>>(afct_h, afct_l, x0fcT_h, x0fcT_l,
                                               x1, nullptr, nullptr,
                                               N_NODES, C_NODES, JPAD, JPAD);
    head2_kernel<<<N_NODES, blk, 0, stream>>>(x1, w1, b1, state, u_buf, out);
}

// Round 5
// 830.140 us; speedup vs baseline: 2.5246x; 1.0559x over previous
//
#include <hip/hip_runtime.h>
#include <hip/hip_bf16.h>
#include <math.h>

#define N_NODES 2048
#define C_NODES 256
#define BATCH   64
#define UNITS   64
#define JS      4096                // state-part columns: j = b*64+u  (no pad!)
#define NU      131072              // N_NODES * UNITS
#define BPAD    128                 // padded batch for input-channel GEMMs

typedef short  s16x8 __attribute__((ext_vector_type(8)));   // 8 bf16 in 4 VGPRs
typedef float  f32x4 __attribute__((ext_vector_type(4)));

__device__ __forceinline__ float sigmoidf_(float x) { return 1.0f / (1.0f + __expf(-x)); }

__device__ __forceinline__ void gload_lds16(const void* g, void* l) {
    __builtin_amdgcn_global_load_lds(
        (const __attribute__((address_space(1))) void*)g,
        (__attribute__((address_space(3))) void*)l, 16, 0, 0);
}

// ---------------- converts ----------------
__global__ __launch_bounds__(256) void cvt_bf16(const float* __restrict__ s,
                                                __hip_bfloat16* __restrict__ d, int n)
{
    int stride = gridDim.x * 256;
    for (int i = blockIdx.x * 256 + threadIdx.x; i < n; i += stride)
        d[i] = __float2bfloat16(s[i]);
}

__global__ __launch_bounds__(256) void cvt_split(const float* __restrict__ s,
                                                 __hip_bfloat16* __restrict__ dh,
                                                 __hip_bfloat16* __restrict__ dl, int n)
{
    int stride = gridDim.x * 256;
    for (int i = blockIdx.x * 256 + threadIdx.x; i < n; i += stride) {
        float v = s[i];
        __hip_bfloat16 h = __float2bfloat16(v);
        dh[i] = h;
        dl[i] = __float2bfloat16(v - __bfloat162float(h));
    }
}

// inputs [64][2048] -> inp_h/l [BPAD][2048], rows 64..127 zero
__global__ __launch_bounds__(256) void cvt_inp(const float* __restrict__ inputs,
                                               __hip_bfloat16* __restrict__ ih,
                                               __hip_bfloat16* __restrict__ il)
{
    int b = blockIdx.x;
    for (int m = threadIdx.x; m < N_NODES; m += 256) {
        float v = (b < BATCH) ? inputs[(size_t)b * N_NODES + m] : 0.0f;
        __hip_bfloat16 h = __float2bfloat16(v);
        ih[(size_t)b * N_NODES + m] = h;
        il[(size_t)b * N_NODES + m] = __float2bfloat16(v - __bfloat162float(h));
    }
}

// w0[65][128], w1[65][64] -> blocked transposed bf16 h/l: cell (c*O+o), elem jj = w[(1+c*8+jj)*O + o]
__global__ __launch_bounds__(256) void cvt_w(const float* __restrict__ w0,
                                             const float* __restrict__ w1,
                                             __hip_bfloat16* __restrict__ w0h, __hip_bfloat16* __restrict__ w0l,
                                             __hip_bfloat16* __restrict__ w1h, __hip_bfloat16* __restrict__ w1l)
{
    int stride = gridDim.x * 256;
    for (int e = blockIdx.x * 256 + threadIdx.x; e < 8192 + 4096; e += stride) {
        if (e < 8192) {  // w0T: O=128
            int jj = e & 7, cell = e >> 3;
            int o = cell & 127, c = cell >> 7;
            float v = w0[(size_t)(1 + c * 8 + jj) * 128 + o];
            __hip_bfloat16 h = __float2bfloat16(v);
            w0h[e] = h; w0l[e] = __float2bfloat16(v - __bfloat162float(h));
        } else {         // w1T: O=64
            int e2 = e - 8192;
            int jj = e2 & 7, cell = e2 >> 3;
            int o = cell & 63, c = cell >> 6;
            float v = w1[(size_t)(1 + c * 8 + jj) * 64 + o];
            __hip_bfloat16 h = __float2bfloat16(v);
            w1h[e2] = h; w1l[e2] = __float2bfloat16(v - __bfloat162float(h));
        }
    }
}

// pass-1 x0sT build: state[b][n*64+u] -> x0sT_h/l[(b*64+u)][n]
__global__ __launch_bounds__(256) void build_x0sT(const float* __restrict__ st,
                                                  __hip_bfloat16* __restrict__ xh,
                                                  __hip_bfloat16* __restrict__ xl)
{
    __shared__ float Ls[64 * 65];
    int n0 = blockIdx.x * 64;
    int b  = blockIdx.y;
    int t  = threadIdx.x;
    #pragma unroll
    for (int it = 0; it < 16; it++) {
        int idx = t + it * 256;
        int i = idx >> 6, u = idx & 63;
        Ls[i * 65 + u] = st[(size_t)b * NU + (size_t)(n0 + i) * 64 + u];
    }
    __syncthreads();
    #pragma unroll
    for (int it = 0; it < 16; it++) {
        int idx = t + it * 256;
        int u = idx >> 6, i = idx & 63;
        float v = Ls[i * 65 + u];
        __hip_bfloat16 h = __float2bfloat16(v);
        size_t o = (size_t)(b * 64 + u) * N_NODES + n0 + i;
        xh[o] = h;
        xl[o] = __float2bfloat16(v - __bfloat162float(h));
    }
}

// ---------------- plain bf16 MFMA GEMM: Out[M][N] = A[M][K] @ Bt[N][K]^T ----------------
// EPI: 0 = fp32 store, 2 = bf16 hi/lo pair store
template<int EPI>
__global__ __launch_bounds__(256, 2) void gemm_mfma(
    const __hip_bfloat16* __restrict__ A,
    const __hip_bfloat16* __restrict__ Bt,
    float* __restrict__ OutF, __hip_bfloat16* __restrict__ OutH, __hip_bfloat16* __restrict__ OutL,
    int M, int K, int N, int ldOut)
{
    __shared__ __align__(16) __hip_bfloat16 As[8192];
    __shared__ __align__(16) __hip_bfloat16 Bs[8192];

    int tid  = threadIdx.x;
    int wave = tid >> 6, lane = tid & 63;
    int quad = lane >> 4, lr = lane & 15;
    int wr = wave >> 1, wc = wave & 1;
    int mBase = blockIdx.y * 128, nBase = blockIdx.x * 128;

    const __hip_bfloat16* gA[4]; const __hip_bfloat16* gB[4];
    __hip_bfloat16* lA[4]; __hip_bfloat16* lB[4];
    #pragma unroll
    for (int ch = 0; ch < 4; ch++) {
        int cell = (wave * 4 + ch) * 64 + lane;
        int kb = cell >> 7, mm = cell & 127;
        gA[ch] = A  + (size_t)(mBase + mm) * K + kb * 8;
        gB[ch] = Bt + (size_t)(nBase + mm) * K + kb * 8;
        lA[ch] = As + (wave * 4 + ch) * 512;
        lB[ch] = Bs + (wave * 4 + ch) * 512;
    }

    f32x4 acc[4][4];
    #pragma unroll
    for (int i = 0; i < 4; i++)
        #pragma unroll
        for (int j = 0; j < 4; j++) { f32x4 z = {0.f,0.f,0.f,0.f}; acc[i][j] = z; }

    for (int k0 = 0; k0 < K; k0 += 64) {
        #pragma unroll
        for (int ch = 0; ch < 4; ch++) {
            gload_lds16(gA[ch] + k0, lA[ch]);
            gload_lds16(gB[ch] + k0, lB[ch]);
        }
        __syncthreads();
        const s16x8* AsV = (const s16x8*)As;
        const s16x8* BsV = (const s16x8*)Bs;
        #pragma unroll
        for (int ks = 0; ks < 2; ks++) {
            int kb = ks * 4 + quad;
            s16x8 af[4], bfr[4];
            #pragma unroll
            for (int i = 0; i < 4; i++) af[i]  = AsV[kb * 128 + wr * 64 + i * 16 + lr];
            #pragma unroll
            for (int j = 0; j < 4; j++) bfr[j] = BsV[kb * 128 + wc * 64 + j * 16 + lr];
            #pragma unroll
            for (int i = 0; i < 4; i++)
                #pragma unroll
                for (int j = 0; j < 4; j++)
                    acc[i][j] = __builtin_amdgcn_mfma_f32_16x16x32_bf16(af[i], bfr[j], acc[i][j], 0, 0, 0);
        }
        __syncthreads();
    }

    #pragma unroll
    for (int i = 0; i < 4; i++)
        #pragma unroll
        for (int j = 0; j < 4; j++)
            #pragma unroll
            for (int r = 0; r < 4; r++) {
                int row = mBase + wr * 64 + i * 16 + quad * 4 + r;
                int col = nBase + wc * 64 + j * 16 + lr;
                size_t idx = (size_t)row * ldOut + col;
                float v = acc[i][j][r];
                if (EPI == 0) OutF[idx] = v;
                else {
                    __hip_bfloat16 h = __float2bfloat16(v);
                    OutH[idx] = h;
                    OutL[idx] = __float2bfloat16(v - __bfloat162float(h));
                }
            }
}

// ---------------- split (hi/lo) MFMA GEMM ----------------
// acc = Ah*Bh + Ah*Bl + Al*Bh
// EPI: 1 = store hi/lo pair; 2 = OutF += sigmoid(acc); 3 = hi/lo pair RMW += sigmoid(acc)
template<int EPI>
__global__ __launch_bounds__(256, 2) void gemm_mfma_split(
    const __hip_bfloat16* __restrict__ Ah, const __hip_bfloat16* __restrict__ Al,
    const __hip_bfloat16* __restrict__ Bh, const __hip_bfloat16* __restrict__ Bl,
    float* __restrict__ OutF, __hip_bfloat16* __restrict__ OutHi, __hip_bfloat16* __restrict__ OutLo,
    int M, int K, int N, int ldOut)
{
    __shared__ __align__(16) __hip_bfloat16 Ash[8192];
    __shared__ __align__(16) __hip_bfloat16 Asl[8192];
    __shared__ __align__(16) __hip_bfloat16 Bsh[8192];
    __shared__ __align__(16) __hip_bfloat16 Bsl[8192];

    int tid  = threadIdx.x;
    int wave = tid >> 6, lane = tid & 63;
    int quad = lane >> 4, lr = lane & 15;
    int wr = wave >> 1, wc = wave & 1;
    int mBase = blockIdx.y * 128, nBase = blockIdx.x * 128;

    const __hip_bfloat16 *gAh[4], *gAl[4], *gBh[4], *gBl[4];
    __hip_bfloat16 *lAh[4], *lAl[4], *lBh[4], *lBl[4];
    #pragma unroll
    for (int ch = 0; ch < 4; ch++) {
        int cell = (wave * 4 + ch) * 64 + lane;
        int kb = cell >> 7, mm = cell & 127;
        size_t offA = (size_t)(mBase + mm) * K + kb * 8;
        size_t offB = (size_t)(nBase + mm) * K + kb * 8;
        gAh[ch] = Ah + offA; gAl[ch] = Al + offA;
        gBh[ch] = Bh + offB; gBl[ch] = Bl + offB;
        int lo = (wave * 4 + ch) * 512;
        lAh[ch] = Ash + lo; lAl[ch] = Asl + lo;
        lBh[ch] = Bsh + lo; lBl[ch] = Bsl + lo;
    }

    f32x4 acc[4][4];
    #pragma unroll
    for (int i = 0; i < 4; i++)
        #pragma unroll
        for (int j = 0; j < 4; j++) { f32x4 z = {0.f,0.f,0.f,0.f}; acc[i][j] = z; }

    for (int k0 = 0; k0 < K; k0 += 64) {
        #pragma unroll
        for (int ch = 0; ch < 4; ch++) {
            gload_lds16(gAh[ch] + k0, lAh[ch]);
            gload_lds16(gAl[ch] + k0, lAl[ch]);
            gload_lds16(gBh[ch] + k0, lBh[ch]);
            gload_lds16(gBl[ch] + k0, lBl[ch]);
        }
        __syncthreads();
        const s16x8* AhV = (const s16x8*)Ash;
        const s16x8* AlV = (const s16x8*)Asl;
        const s16x8* BhV = (const s16x8*)Bsh;
        const s16x8* BlV = (const s16x8*)Bsl;
        #pragma unroll
        for (int ks = 0; ks < 2; ks++) {
            int kb = ks * 4 + quad;
            s16x8 ah[4], al[4], bh[4], bl[4];
            #pragma unroll
            for (int i = 0; i < 4; i++) {
                int idx = kb * 128 + wr * 64 + i * 16 + lr;
                ah[i] = AhV[idx]; al[i] = AlV[idx];
            }
            #pragma unroll
            for (int j = 0; j < 4; j++) {
                int idx = kb * 128 + wc * 64 + j * 16 + lr;
                bh[j] = BhV[idx]; bl[j] = BlV[idx];
            }
            #pragma unroll
            for (int i = 0; i < 4; i++)
                #pragma unroll
                for (int j = 0; j < 4; j++) {
                    acc[i][j] = __builtin_amdgcn_mfma_f32_16x16x32_bf16(ah[i], bh[j], acc[i][j], 0, 0, 0);
                    acc[i][j] = __builtin_amdgcn_mfma_f32_16x16x32_bf16(ah[i], bl[j], acc[i][j], 0, 0, 0);
                    acc[i][j] = __builtin_amdgcn_mfma_f32_16x16x32_bf16(al[i], bh[j], acc[i][j], 0, 0, 0);
                }
        }
        __syncthreads();
    }

    #pragma unroll
    for (int i = 0; i < 4; i++)
        #pragma unroll
        for (int j = 0; j < 4; j++)
            #pragma unroll
            for (int r = 0; r < 4; r++) {
                int row = mBase + wr * 64 + i * 16 + quad * 4 + r;
                int col = nBase + wc * 64 + j * 16 + lr;
                float v = acc[i][j][r];
                size_t idx = (size_t)row * ldOut + col;
                if (EPI == 1) {
                    __hip_bfloat16 h = __float2bfloat16(v);
                    OutHi[idx] = h;
                    OutLo[idx] = __float2bfloat16(v - __bfloat162float(h));
                } else if (EPI == 2) {
                    OutF[idx] = OutF[idx] + sigmoidf_(v);
                } else {
                    float old = __bfloat162float(OutHi[idx]) + __bfloat162float(OutLo[idx]);
                    float nv = old + sigmoidf_(v);
                    __hip_bfloat16 h = __float2bfloat16(nv);
                    OutHi[idx] = h;
                    OutLo[idx] = __float2bfloat16(nv - __bfloat162float(h));
                }
            }
}

// ---------------- head1 (split MFMA): gates = x1s @ w0T + w0_row0*xin + b0 ----------------
// tile: 128 n x 128 o, one b per block. wc=0 waves: r-gates -> x0sT h/l via LDS transpose.
// wc=1 waves: u-gates -> u_buf[b][n][o-64] (bf16).
__global__ __launch_bounds__(256) void head1_mfma(
    const __hip_bfloat16* __restrict__ x1h, const __hip_bfloat16* __restrict__ x1l,
    const float* __restrict__ xin1,
    const __hip_bfloat16* __restrict__ Wh, const __hip_bfloat16* __restrict__ Wl,
    const float* __restrict__ w0, const float* __restrict__ b0,
    const float* __restrict__ state,
    __hip_bfloat16* __restrict__ xh, __hip_bfloat16* __restrict__ xl,
    __hip_bfloat16* __restrict__ u_buf)
{
    __shared__ __align__(16) __hip_bfloat16 XsH[8192];   // 16 KB each
    __shared__ __align__(16) __hip_bfloat16 XsL[8192];
    __shared__ __align__(16) __hip_bfloat16 WhS[8192];
    __shared__ __align__(16) __hip_bfloat16 WlS[8192];   // 64 KB total

    int n0 = blockIdx.x * 128;
    int b  = blockIdx.y;
    int tid = threadIdx.x;
    int wave = tid >> 6, lane = tid & 63;
    int quad = lane >> 4, lr = lane & 15;
    int wr = wave >> 1, wc = wave & 1;

    #pragma unroll
    for (int ch = 0; ch < 4; ch++) {
        int idx = (wave * 4 + ch) * 64 + lane;
        int c = idx >> 7, n = idx & 127;
        size_t gx = (size_t)(n0 + n) * JS + b * 64 + c * 8;
        gload_lds16(x1h + gx, XsH + (wave * 4 + ch) * 512);
        gload_lds16(x1l + gx, XsL + (wave * 4 + ch) * 512);
        gload_lds16(Wh + (size_t)idx * 8, WhS + (wave * 4 + ch) * 512);
        gload_lds16(Wl + (size_t)idx * 8, WlS + (wave * 4 + ch) * 512);
    }
    __syncthreads();

    f32x4 acc[4][4];
    #pragma unroll
    for (int i = 0; i < 4; i++)
        #pragma unroll
        for (int j = 0; j < 4; j++) { f32x4 z = {0.f,0.f,0.f,0.f}; acc[i][j] = z; }

    const s16x8* XhV = (const s16x8*)XsH;
    const s16x8* XlV = (const s16x8*)XsL;
    const s16x8* WhV = (const s16x8*)WhS;
    const s16x8* WlV = (const s16x8*)WlS;
    #pragma unroll
    for (int ks = 0; ks < 2; ks++) {
        int kb = ks * 4 + quad;
        s16x8 ah[4], al[4], bh[4], bl[4];
        #pragma unroll
        for (int i = 0; i < 4; i++) {
            int idx = kb * 128 + wr * 64 + i * 16 + lr;
            ah[i] = XhV[idx]; al[i] = XlV[idx];
        }
        #pragma unroll
        for (int j = 0; j < 4; j++) {
            int idx = kb * 128 + wc * 64 + j * 16 + lr;
            bh[j] = WhV[idx]; bl[j] = WlV[idx];
        }
        #pragma unroll
        for (int i = 0; i < 4; i++)
            #pragma unroll
            for (int j = 0; j < 4; j++) {
                acc[i][j] = __builtin_amdgcn_mfma_f32_16x16x32_bf16(ah[i], bh[j], acc[i][j], 0, 0, 0);
                acc[i][j] = __builtin_amdgcn_mfma_f32_16x16x32_bf16(ah[i], bl[j], acc[i][j], 0, 0, 0);
                acc[i][j] = __builtin_amdgcn_mfma_f32_16x16x32_bf16(al[i], bh[j], acc[i][j], 0, 0, 0);
            }
    }
    __syncthreads();   // frag reads done; reuse XsH/XsL as transpose buffers

    __hip_bfloat16* trH = XsH;   // [64 o][128 n]
    __hip_bfloat16* trL = XsL;

    #pragma unroll
    for (int i = 0; i < 4; i++)
        #pragma unroll
        for (int j = 0; j < 4; j++)
            #pragma unroll
            for (int r = 0; r < 4; r++) {
                int n_loc = wr * 64 + i * 16 + quad * 4 + r;
                int o = wc * 64 + j * 16 + lr;
                float xin = xin1[(size_t)(n0 + n_loc) * BPAD + b];
                float g = acc[i][j][r] + w0[o] * xin + b0[o];
                float sg = sigmoidf_(g);
                if (wc == 0) {
                    float sv = state[(size_t)b * NU + (size_t)(n0 + n_loc) * 64 + o];
                    float rs = sg * sv;
                    __hip_bfloat16 h = __float2bfloat16(rs);
                    trH[o * 128 + n_loc] = h;
                    trL[o * 128 + n_loc] = __float2bfloat16(rs - __bfloat162float(h));
                } else {
                    u_buf[(size_t)b * NU + (size_t)(n0 + n_loc) * 64 + (o - 64)] = __float2bfloat16(sg);
                }
            }
    __syncthreads();

    // coalesced write-out of r*state hi/lo: 64 rows (o) x 128 n
    {
        int row = tid >> 2, seg = tid & 3;
        const uint4* sh = (const uint4*)(trH + row * 128 + seg * 32);
        const uint4* sl = (const uint4*)(trL + row * 128 + seg * 32);
        uint4* dh = (uint4*)(xh + (size_t)(b * 64 + row) * N_NODES + n0 + seg * 32);
        uint4* dl = (uint4*)(xl + (size_t)(b * 64 + row) * N_NODES + n0 + seg * 32);
        #pragma unroll
        for (int q = 0; q < 4; q++) { dh[q] = sh[q]; dl[q] = sl[q]; }
    }
}

// ---------------- head2 (split MFMA): c0 = x1s @ w1T + w1_row0*xin + b1; out = u*s + (1-u)*tanh(c0) ----------------
__global__ __launch_bounds__(256) void head2_mfma(
    const __hip_bfloat16* __restrict__ x1h, const __hip_bfloat16* __restrict__ x1l,
    const float* __restrict__ xin1,
    const __hip_bfloat16* __restrict__ Wh, const __hip_bfloat16* __restrict__ Wl,
    const float* __restrict__ w1, const float* __restrict__ b1,
    const float* __restrict__ state, const __hip_bfloat16* __restrict__ u_buf,
    float* __restrict__ out)
{
    __shared__ __align__(16) __hip_bfloat16 XsH[8192];
    __shared__ __align__(16) __hip_bfloat16 XsL[8192];
    __shared__ __align__(16) __hip_bfloat16 WhS[4096];
    __shared__ __align__(16) __hip_bfloat16 WlS[4096];   // 48 KB total

    int n0 = blockIdx.x * 128;
    int b  = blockIdx.y;
    int tid = threadIdx.x;
    int wave = tid >> 6, lane = tid & 63;
    int quad = lane >> 4, lr = lane & 15;

    #pragma unroll
    for (int ch = 0; ch < 4; ch++) {
        int idx = (wave * 4 + ch) * 64 + lane;
        int c = idx >> 7, n = idx & 127;
        size_t gx = (size_t)(n0 + n) * JS + b * 64 + c * 8;
        gload_lds16(x1h + gx, XsH + (wave * 4 + ch) * 512);
        gload_lds16(x1l + gx, XsL + (wave * 4 + ch) * 512);
    }
    #pragma unroll
    for (int ch = 0; ch < 2; ch++) {
        int idx = (wave * 2 + ch) * 64 + lane;
        gload_lds16(Wh + (size_t)idx * 8, WhS + (wave * 2 + ch) * 512);
        gload_lds16(Wl + (size_t)idx * 8, WlS + (wave * 2 + ch) * 512);
    }
    __syncthreads();

    f32x4 acc[2][4];
    #pragma unroll
    for (int i = 0; i < 2; i++)
        #pragma unroll
        for (int j = 0; j < 4; j++) { f32x4 z = {0.f,0.f,0.f,0.f}; acc[i][j] = z; }

    const s16x8* XhV = (const s16x8*)XsH;
    const s16x8* XlV = (const s16x8*)XsL;
    const s16x8* WhV = (const s16x8*)WhS;
    const s16x8* WlV = (const s16x8*)WlS;
    #pragma unroll
    for (int ks = 0; ks < 2; ks++) {
        int kb = ks * 4 + quad;
        s16x8 ah[2], al[2], bh[4], bl[4];
        #pragma unroll
        for (int i = 0; i < 2; i++) {
            int idx = kb * 128 + wave * 32 + i * 16 + lr;
            ah[i] = XhV[idx]; al[i] = XlV[idx];
        }
        #pragma unroll
        for (int j = 0; j < 4; j++) {
            int idx = kb * 64 + j * 16 + lr;
            bh[j] = WhV[idx]; bl[j] = WlV[idx];
        }
        #pragma unroll
        for (int i = 0; i < 2; i++)
            #pragma unroll
            for (int j = 0; j < 4; j++) {
                acc[i][j] = __builtin_amdgcn_mfma_f32_16x16x32_bf16(ah[i], bh[j], acc[i][j], 0, 0, 0);
                acc[i][j] = __builtin_amdgcn_mfma_f32_16x16x32_bf16(ah[i], bl[j], acc[i][j], 0, 0, 0);
                acc[i][j] = __builtin_amdgcn_mfma_f32_16x16x32_bf16(al[i], bh[j], acc[i][j], 0, 0, 0);
            }
    }

    #pragma unroll
    for (int i = 0; i < 2; i++)
        #pragma unroll
        for (int j = 0; j < 4; j++)
            #pragma unroll
            for (int r = 0; r < 4; r++) {
                int n_loc = wave * 32 + i * 16 + quad * 4 + r;
                int o = j * 16 + lr;
                float xin = xin1[(size_t)(n0 + n_loc) * BPAD + b];
                float g = acc[i][j][r] + w1[o] * xin + b1[o];
                float c = tanhf(g);
                size_t sidx = (size_t)b * NU + (size_t)(n0 + n_loc) * 64 + o;
                float ug = __bfloat162float(u_buf[sidx]);
                float sv = state[sidx];
                out[sidx] = ug * sv + (1.0f - ug) * c;
            }
}

extern "C" void kernel_launch(void* const* d_in, const int* in_sizes, int n_in,
                              void* d_out, int out_size, void* d_ws, size_t ws_size,
                              hipStream_t stream)
{
    const float* inputs = (const float*)d_in[0];
    const float* state  = (const float*)d_in[1];
    const float* adj    = (const float*)d_in[2];
    // d_in[3] = adj1 : unused (discarded outfc path)
    const float* afc    = (const float*)d_in[4];   // [C][N]
    const float* afct   = (const float*)d_in[5];   // [N][C]
    const float* w0     = (const float*)d_in[6];
    const float* b0     = (const float*)d_in[7];
    const float* w1     = (const float*)d_in[8];
    const float* b1     = (const float*)d_in[9];
    // d_in[10..13]: unused

    float* out = (float*)d_out;

    char* p = (char*)d_ws;
    __hip_bfloat16* adj_b    = (__hip_bfloat16*)p; p += (size_t)N_NODES * N_NODES * 2;   // 8.39 MB
    __hip_bfloat16* afc_h    = (__hip_bfloat16*)p; p += (size_t)C_NODES * N_NODES * 2;
    __hip_bfloat16* afc_l    = (__hip_bfloat16*)p; p += (size_t)C_NODES * N_NODES * 2;
    __hip_bfloat16* afct_h   = (__hip_bfloat16*)p; p += (size_t)N_NODES * C_NODES * 2;
    __hip_bfloat16* afct_l   = (__hip_bfloat16*)p; p += (size_t)N_NODES * C_NODES * 2;
    __hip_bfloat16* inp_h    = (__hip_bfloat16*)p; p += (size_t)BPAD * N_NODES * 2;
    __hip_bfloat16* inp_l    = (__hip_bfloat16*)p; p += (size_t)BPAD * N_NODES * 2;
    __hip_bfloat16* w0T_h    = (__hip_bfloat16*)p; p += 8192 * 2;
    __hip_bfloat16* w0T_l    = (__hip_bfloat16*)p; p += 8192 * 2;
    __hip_bfloat16* w1T_h    = (__hip_bfloat16*)p; p += 4096 * 2;
    __hip_bfloat16* w1T_l    = (__hip_bfloat16*)p; p += 4096 * 2;
    __hip_bfloat16* x0sT_h   = (__hip_bfloat16*)p; p += (size_t)JS * N_NODES * 2;        // 16.78 MB
    __hip_bfloat16* x0sT_l   = (__hip_bfloat16*)p; p += (size_t)JS * N_NODES * 2;
    __hip_bfloat16* x0fcT_h  = (__hip_bfloat16*)p; p += (size_t)JS * C_NODES * 2;        // 2.10 MB
    __hip_bfloat16* x0fcT_l  = (__hip_bfloat16*)p; p += (size_t)JS * C_NODES * 2;
    __hip_bfloat16* xfc_in_h = (__hip_bfloat16*)p; p += (size_t)BPAD * C_NODES * 2;
    __hip_bfloat16* xfc_in_l = (__hip_bfloat16*)p; p += (size_t)BPAD * C_NODES * 2;
    __hip_bfloat16* x1s_h    = (__hip_bfloat16*)p; p += (size_t)N_NODES * JS * 2;        // 16.78 MB
    __hip_bfloat16* x1s_l    = (__hip_bfloat16*)p; p += (size_t)N_NODES * JS * 2;        // 16.78 MB
    float*          xin1     = (float*)p;          p += (size_t)N_NODES * BPAD * 4;      // 1.05 MB
    __hip_bfloat16* u_buf    = (__hip_bfloat16*)p; p += (size_t)BATCH * NU * 2;          // 16.78 MB
    // total ~103 MB

    dim3 blk(256);

    // ---- once: converts ----
    cvt_bf16 <<<1024, blk, 0, stream>>>(adj,  adj_b, N_NODES * N_NODES);
    cvt_split<<<256,  blk, 0, stream>>>(afc,  afc_h,  afc_l,  C_NODES * N_NODES);
    cvt_split<<<256,  blk, 0, stream>>>(afct, afct_h, afct_l, N_NODES * C_NODES);
    cvt_inp  <<<BPAD, blk, 0, stream>>>(inputs, inp_h, inp_l);
    cvt_w    <<<32,   blk, 0, stream>>>(w0, w1, w0T_h, w0T_l, w1T_h, w1T_l);

    // ---- once: input-channel contribution x1_in = adj@inpT + sigmoid(afct@(afc@inpT)) ----
    gemm_mfma<0><<<dim3(1, 16), blk, 0, stream>>>(adj_b, inp_h, xin1, nullptr, nullptr,
                                                  N_NODES, N_NODES, BPAD, BPAD);
    gemm_mfma_split<1><<<dim3(2, 1), blk, 0, stream>>>(inp_h, inp_l, afc_h, afc_l,
                                                       nullptr, xfc_in_h, xfc_in_l,
                                                       BPAD, N_NODES, C_NODES, C_NODES);
    gemm_mfma_split<2><<<dim3(1, 16), blk, 0, stream>>>(afct_h, afct_l, xfc_in_h, xfc_in_l,
                                                        xin1, nullptr, nullptr,
                                                        N_NODES, C_NODES, BPAD, BPAD);

    // ---- pass 1 ----
    build_x0sT<<<dim3(32, 64), blk, 0, stream>>>(state, x0sT_h, x0sT_l);
    gemm_mfma_split<1><<<dim3(2, 32), blk, 0, stream>>>(x0sT_h, x0sT_l, afc_h, afc_l,
                                                        nullptr, x0fcT_h, x0fcT_l,
                                                        JS, N_NODES, C_NODES, C_NODES);
    gemm_mfma<2><<<dim3(32, 16), blk, 0, stream>>>(adj_b, x0sT_h, nullptr, x1s_h, x1s_l,
                                                   N_NODES, N_NODES, JS, JS);
    gemm_mfma_split<3><<<dim3(32, 16), blk, 0, stream>>>(afct_h, afct_l, x0fcT_h, x0fcT_l,
                                                         nullptr, x1s_h, x1s_l,
                                                         N_NODES, C_NODES, JS, JS);
    head1_mfma<<<dim3(16, 64), blk, 0, stream>>>(x1s_h, x1s_l, xin1, w0T_h, w0T_l, w0, b0,
                                                 state, x0sT_h, x0sT_l, u_buf);

    // ---- pass 2 (x0sT now holds r*state hi/lo, written by head1) ----
    gemm_mfma_split<1><<<dim3(2, 32), blk, 0, stream>>>(x0sT_h, x0sT_l, afc_h, afc_l,
                                                        nullptr, x0fcT_h, x0fcT_l,
                                                        JS, N_NODES, C_NODES, C_NODES);
    gemm_mfma<2><<<dim3(32, 16), blk, 0, stream>>>(adj_b, x0sT_h, nullptr, x1s_h, x1s_l,
                                                   N_NODES, N_NODES, JS, JS);
    gemm_mfma_split<3><<<dim3(32, 16), blk, 0, stream>>>(afct_h, afct_l, x0fcT_h, x0fcT_l,
                                                         nullptr, x1s_h, x1s_l,
                                                         N_NODES, C_NODES, JS, JS);
    head2_mfma<<<dim3(16, 64), blk, 0, stream>>>(x1s_h, x1s_l, xin1, w1T_h, w1T_l, w1, b1,
                                                 state, u_buf, out);
}

// Round 6
// 712.533 us; speedup vs baseline: 2.9413x; 1.1651x over previous
//
#include <hip/hip_runtime.h>
#include <hip/hip_bf16.h>
#include <math.h>

#define N_NODES 2048
#define C_NODES 256
#define BATCH   64
#define UNITS   64
#define JS      4096                // state-part columns: j = b*64+u
#define NU      131072              // N_NODES * UNITS

typedef short  s16x8 __attribute__((ext_vector_type(8)));   // 8 bf16 in 4 VGPRs
typedef float  f32x4 __attribute__((ext_vector_type(4)));

__device__ __forceinline__ float sigmoidf_(float x) { return 1.0f / (1.0f + __expf(-x)); }

__device__ __forceinline__ void gload_lds16(const void* g, void* l) {
    __builtin_amdgcn_global_load_lds(
        (const __attribute__((address_space(1))) void*)g,
        (__attribute__((address_space(3))) void*)l, 16, 0, 0);
}

// ---------------- converts ----------------
__global__ __launch_bounds__(256) void cvt_bf16(const float* __restrict__ s,
                                                __hip_bfloat16* __restrict__ d, int n)
{
    int stride = gridDim.x * 256;
    for (int i = blockIdx.x * 256 + threadIdx.x; i < n; i += stride)
        d[i] = __float2bfloat16(s[i]);
}

__global__ __launch_bounds__(256) void cvt_split(const float* __restrict__ s,
                                                 __hip_bfloat16* __restrict__ dh,
                                                 __hip_bfloat16* __restrict__ dl, int n)
{
    int stride = gridDim.x * 256;
    for (int i = blockIdx.x * 256 + threadIdx.x; i < n; i += stride) {
        float v = s[i];
        __hip_bfloat16 h = __float2bfloat16(v);
        dh[i] = h;
        dl[i] = __float2bfloat16(v - __bfloat162float(h));
    }
}

// w0[65][128], w1[65][64] -> blocked transposed bf16 h/l: cell (c*O+o), elem jj = w[(1+c*8+jj)*O + o]
__global__ __launch_bounds__(256) void cvt_w(const float* __restrict__ w0,
                                             const float* __restrict__ w1,
                                             __hip_bfloat16* __restrict__ w0h, __hip_bfloat16* __restrict__ w0l,
                                             __hip_bfloat16* __restrict__ w1h, __hip_bfloat16* __restrict__ w1l)
{
    int stride = gridDim.x * 256;
    for (int e = blockIdx.x * 256 + threadIdx.x; e < 8192 + 4096; e += stride) {
        if (e < 8192) {  // w0T: O=128
            int jj = e & 7, cell = e >> 3;
            int o = cell & 127, c = cell >> 7;
            float v = w0[(size_t)(1 + c * 8 + jj) * 128 + o];
            __hip_bfloat16 h = __float2bfloat16(v);
            w0h[e] = h; w0l[e] = __float2bfloat16(v - __bfloat162float(h));
        } else {         // w1T: O=64
            int e2 = e - 8192;
            int jj = e2 & 7, cell = e2 >> 3;
            int o = cell & 63, c = cell >> 6;
            float v = w1[(size_t)(1 + c * 8 + jj) * 64 + o];
            __hip_bfloat16 h = __float2bfloat16(v);
            w1h[e2] = h; w1l[e2] = __float2bfloat16(v - __bfloat162float(h));
        }
    }
}

// pass-1 x0sT build: state[b][n*64+u] -> x0sT_h/l[(b*64+u)][n]
__global__ __launch_bounds__(256) void build_x0sT(const float* __restrict__ st,
                                                  __hip_bfloat16* __restrict__ xh,
                                                  __hip_bfloat16* __restrict__ xl)
{
    __shared__ float Ls[64 * 65];
    int n0 = blockIdx.x * 64;
    int b  = blockIdx.y;
    int t  = threadIdx.x;
    #pragma unroll
    for (int it = 0; it < 16; it++) {
        int idx = t + it * 256;
        int i = idx >> 6, u = idx & 63;
        Ls[i * 65 + u] = st[(size_t)b * NU + (size_t)(n0 + i) * 64 + u];
    }
    __syncthreads();
    #pragma unroll
    for (int it = 0; it < 16; it++) {
        int idx = t + it * 256;
        int u = idx >> 6, i = idx & 63;
        float v = Ls[i * 65 + u];
        __hip_bfloat16 h = __float2bfloat16(v);
        size_t o = (size_t)(b * 64 + u) * N_NODES + n0 + i;
        xh[o] = h;
        xl[o] = __float2bfloat16(v - __bfloat162float(h));
    }
}

// ---------------- input-channel path (exact fp32, once per call) ----------------
// y[c][b] = sum_n afc[c][n] * inp[b][n]
__global__ __launch_bounds__(256) void input_fc(const float* __restrict__ afc,
                                                const float* __restrict__ inp,
                                                float* __restrict__ y)
{
    __shared__ float Ls[256];
    int c = blockIdx.x;
    int t = threadIdx.x;
    int b = t >> 2, part = t & 3;
    float s = 0.f;
    for (int k = part; k < N_NODES; k += 4)
        s += afc[(size_t)c * N_NODES + k] * inp[(size_t)b * N_NODES + k];
    Ls[t] = s;
    __syncthreads();
    if (t < 64)
        y[c * 64 + t] = Ls[4 * t] + Ls[4 * t + 1] + Ls[4 * t + 2] + Ls[4 * t + 3];
}

// xin1[n][b] = sum_k adj[n][k]*inp[b][k] + sigmoid( sum_c afct[n][c]*y[c][b] )
__global__ __launch_bounds__(256) void input_node(const float* __restrict__ adj,
                                                  const float* __restrict__ afct,
                                                  const float* __restrict__ inp,
                                                  const float* __restrict__ y,
                                                  float* __restrict__ xin1)
{
    __shared__ float La[256];
    __shared__ float Lc[256];
    int n = blockIdx.x;
    int t = threadIdx.x;
    int b = t >> 2, part = t & 3;
    float sa = 0.f;
    for (int k = part; k < N_NODES; k += 4)
        sa += adj[(size_t)n * N_NODES + k] * inp[(size_t)b * N_NODES + k];
    float sc = 0.f;
    for (int c = part; c < C_NODES; c += 4)
        sc += afct[(size_t)n * C_NODES + c] * y[c * 64 + b];
    La[t] = sa; Lc[t] = sc;
    __syncthreads();
    if (t < 64) {
        float va = La[4 * t] + La[4 * t + 1] + La[4 * t + 2] + La[4 * t + 3];
        float vc = Lc[4 * t] + Lc[4 * t + 1] + Lc[4 * t + 2] + Lc[4 * t + 3];
        xin1[n * 64 + t] = va + sigmoidf_(vc);
    }
}

// ---------------- GEMM1 (coarse, split-K): part[kp] = x0sT @ afc^T ----------------
// Out[j][c], M=4096(j), N=256(c), K=2048; 64x64 tiles; 3-term split; blockIdx.z = K-half.
__global__ __launch_bounds__(256) void gemm1_split(
    const __hip_bfloat16* __restrict__ Ah, const __hip_bfloat16* __restrict__ Al,
    const __hip_bfloat16* __restrict__ Bh, const __hip_bfloat16* __restrict__ Bl,
    float* __restrict__ part)
{
    __shared__ __align__(16) __hip_bfloat16 AsH[4096];   // 8 KB each
    __shared__ __align__(16) __hip_bfloat16 AsL[4096];
    __shared__ __align__(16) __hip_bfloat16 BsH[4096];
    __shared__ __align__(16) __hip_bfloat16 BsL[4096];   // 32 KB total

    const int K = N_NODES;           // 2048
    int tid  = threadIdx.x;
    int wave = tid >> 6, lane = tid & 63;
    int quad = lane >> 4, lr = lane & 15;
    int mBase = blockIdx.y * 64;     // j
    int nBase = blockIdx.x * 64;     // c
    int k0base = blockIdx.z * (K / 2);

    const __hip_bfloat16 *gAh[2], *gAl[2], *gBh[2], *gBl[2];
    __hip_bfloat16 *lAh[2], *lAl[2], *lBh[2], *lBl[2];
    #pragma unroll
    for (int ch = 0; ch < 2; ch++) {
        int cell = (wave * 2 + ch) * 64 + lane;     // 0..511
        int kb = cell >> 6, mm = cell & 63;         // kb 0..7
        size_t offA = (size_t)(mBase + mm) * K + k0base + kb * 8;
        size_t offB = (size_t)(nBase + mm) * K + k0base + kb * 8;
        gAh[ch] = Ah + offA; gAl[ch] = Al + offA;
        gBh[ch] = Bh + offB; gBl[ch] = Bl + offB;
        int lo = (wave * 2 + ch) * 512;
        lAh[ch] = AsH + lo; lAl[ch] = AsL + lo;
        lBh[ch] = BsH + lo; lBl[ch] = BsL + lo;
    }

    f32x4 acc[4];
    #pragma unroll
    for (int j = 0; j < 4; j++) { f32x4 z = {0.f,0.f,0.f,0.f}; acc[j] = z; }

    for (int k0 = 0; k0 < K / 2; k0 += 64) {
        #pragma unroll
        for (int ch = 0; ch < 2; ch++) {
            gload_lds16(gAh[ch] + k0, lAh[ch]);
            gload_lds16(gAl[ch] + k0, lAl[ch]);
            gload_lds16(gBh[ch] + k0, lBh[ch]);
            gload_lds16(gBl[ch] + k0, lBl[ch]);
        }
        __syncthreads();
        const s16x8* AhV = (const s16x8*)AsH;
        const s16x8* AlV = (const s16x8*)AsL;
        const s16x8* BhV = (const s16x8*)BsH;
        const s16x8* BlV = (const s16x8*)BsL;
        #pragma unroll
        for (int ks = 0; ks < 2; ks++) {
            int kb = ks * 4 + quad;
            s16x8 ah = AhV[kb * 64 + wave * 16 + lr];
            s16x8 al = AlV[kb * 64 + wave * 16 + lr];
            s16x8 bh[4], bl[4];
            #pragma unroll
            for (int j = 0; j < 4; j++) {
                bh[j] = BhV[kb * 64 + j * 16 + lr];
                bl[j] = BlV[kb * 64 + j * 16 + lr];
            }
            #pragma unroll
            for (int j = 0; j < 4; j++) {
                acc[j] = __builtin_amdgcn_mfma_f32_16x16x32_bf16(ah, bh[j], acc[j], 0, 0, 0);
                acc[j] = __builtin_amdgcn_mfma_f32_16x16x32_bf16(ah, bl[j], acc[j], 0, 0, 0);
                acc[j] = __builtin_amdgcn_mfma_f32_16x16x32_bf16(al, bh[j], acc[j], 0, 0, 0);
            }
        }
        __syncthreads();
    }

    float* dst = part + (size_t)blockIdx.z * JS * C_NODES;
    #pragma unroll
    for (int j = 0; j < 4; j++)
        #pragma unroll
        for (int r = 0; r < 4; r++) {
            int row = mBase + wave * 16 + quad * 4 + r;
            int col = nBase + j * 16 + lr;
            dst[(size_t)row * C_NODES + col] = acc[j][r];
        }
}

// reduce two split-K partials -> hi/lo bf16 pair
__global__ __launch_bounds__(256) void reduce_split(const float* __restrict__ part,
                                                    __hip_bfloat16* __restrict__ oh,
                                                    __hip_bfloat16* __restrict__ ol, int n)
{
    int stride = gridDim.x * 256;
    for (int i = blockIdx.x * 256 + threadIdx.x; i < n; i += stride) {
        float v = part[i] + part[(size_t)n + i];
        __hip_bfloat16 h = __float2bfloat16(v);
        oh[i] = h;
        ol[i] = __float2bfloat16(v - __bfloat162float(h));
    }
}

// ---------------- fused per-pass GEMM: x1s = adj@x0s + sigmoid(afct@x0fc) ----------------
// Phase 1 (K=256, 3-term split): acc = afct @ x0fcT^T ; acc = sigmoid(acc)
// Phase 2 (K=2048, plain):       acc += adj @ x0sT^T
// Epilogue: hi/lo bf16 store. M=2048(n) x N=4096(j), 128x128 tiles, grid (32,16).
__global__ __launch_bounds__(256, 2) void gemm_fused(
    const __hip_bfloat16* __restrict__ Ah, const __hip_bfloat16* __restrict__ Al,  // afct h/l [2048][256]
    const __hip_bfloat16* __restrict__ Bh, const __hip_bfloat16* __restrict__ Bl,  // x0fcT h/l [4096][256]
    const __hip_bfloat16* __restrict__ A2, const __hip_bfloat16* __restrict__ B2,  // adj [2048][2048], x0sT_h [4096][2048]
    __hip_bfloat16* __restrict__ OutH, __hip_bfloat16* __restrict__ OutL)
{
    __shared__ __align__(16) __hip_bfloat16 S1[8192];   // A hi (both phases)
    __shared__ __align__(16) __hip_bfloat16 S2[8192];   // A lo (phase 1)
    __shared__ __align__(16) __hip_bfloat16 S3[8192];   // B hi (both phases)
    __shared__ __align__(16) __hip_bfloat16 S4[8192];   // B lo (phase 1)  -- 64 KB

    int tid  = threadIdx.x;
    int wave = tid >> 6, lane = tid & 63;
    int quad = lane >> 4, lr = lane & 15;
    int wr = wave >> 1, wc = wave & 1;
    int mBase = blockIdx.y * 128, nBase = blockIdx.x * 128;

    int cellkb[4], cellmm[4];
    #pragma unroll
    for (int ch = 0; ch < 4; ch++) {
        int cell = (wave * 4 + ch) * 64 + lane;   // 0..1023
        cellkb[ch] = cell >> 7;                   // 0..7
        cellmm[ch] = cell & 127;
    }

    f32x4 acc[4][4];
    #pragma unroll
    for (int i = 0; i < 4; i++)
        #pragma unroll
        for (int j = 0; j < 4; j++) { f32x4 z = {0.f,0.f,0.f,0.f}; acc[i][j] = z; }

    // ---- phase 1: coarse, K=256, split 3-term ----
    for (int k0 = 0; k0 < C_NODES; k0 += 64) {
        #pragma unroll
        for (int ch = 0; ch < 4; ch++) {
            size_t offA = (size_t)(mBase + cellmm[ch]) * C_NODES + k0 + cellkb[ch] * 8;
            size_t offB = (size_t)(nBase + cellmm[ch]) * C_NODES + k0 + cellkb[ch] * 8;
            int lo = (wave * 4 + ch) * 512;
            gload_lds16(Ah + offA, S1 + lo);
            gload_lds16(Al + offA, S2 + lo);
            gload_lds16(Bh + offB, S3 + lo);
            gload_lds16(Bl + offB, S4 + lo);
        }
        __syncthreads();
        const s16x8* AhV = (const s16x8*)S1;
        const s16x8* AlV = (const s16x8*)S2;
        const s16x8* BhV = (const s16x8*)S3;
        const s16x8* BlV = (const s16x8*)S4;
        #pragma unroll
        for (int ks = 0; ks < 2; ks++) {
            int kb = ks * 4 + quad;
            s16x8 ah[4], al[4], bh[4], bl[4];
            #pragma unroll
            for (int i = 0; i < 4; i++) {
                int idx = kb * 128 + wr * 64 + i * 16 + lr;
                ah[i] = AhV[idx]; al[i] = AlV[idx];
            }
            #pragma unroll
            for (int j = 0; j < 4; j++) {
                int idx = kb * 128 + wc * 64 + j * 16 + lr;
                bh[j] = BhV[idx]; bl[j] = BlV[idx];
            }
            #pragma unroll
            for (int i = 0; i < 4; i++)
                #pragma unroll
                for (int j = 0; j < 4; j++) {
                    acc[i][j] = __builtin_amdgcn_mfma_f32_16x16x32_bf16(ah[i], bh[j], acc[i][j], 0, 0, 0);
                    acc[i][j] = __builtin_amdgcn_mfma_f32_16x16x32_bf16(ah[i], bl[j], acc[i][j], 0, 0, 0);
                    acc[i][j] = __builtin_amdgcn_mfma_f32_16x16x32_bf16(al[i], bh[j], acc[i][j], 0, 0, 0);
                }
        }
        __syncthreads();
    }

    // sigmoid in registers
    #pragma unroll
    for (int i = 0; i < 4; i++)
        #pragma unroll
        for (int j = 0; j < 4; j++)
            #pragma unroll
            for (int r = 0; r < 4; r++)
                acc[i][j][r] = sigmoidf_(acc[i][j][r]);

    // ---- phase 2: adj, K=2048, plain bf16, accumulate onto acc ----
    for (int k0 = 0; k0 < N_NODES; k0 += 64) {
        #pragma unroll
        for (int ch = 0; ch < 4; ch++) {
            size_t offA = (size_t)(mBase + cellmm[ch]) * N_NODES + k0 + cellkb[ch] * 8;
            size_t offB = (size_t)(nBase + cellmm[ch]) * N_NODES + k0 + cellkb[ch] * 8;
            int lo = (wave * 4 + ch) * 512;
            gload_lds16(A2 + offA, S1 + lo);
            gload_lds16(B2 + offB, S3 + lo);
        }
        __syncthreads();
        const s16x8* AsV = (const s16x8*)S1;
        const s16x8* BsV = (const s16x8*)S3;
        #pragma unroll
        for (int ks = 0; ks < 2; ks++) {
            int kb = ks * 4 + quad;
            s16x8 af[4], bfr[4];
            #pragma unroll
            for (int i = 0; i < 4; i++) af[i]  = AsV[kb * 128 + wr * 64 + i * 16 + lr];
            #pragma unroll
            for (int j = 0; j < 4; j++) bfr[j] = BsV[kb * 128 + wc * 64 + j * 16 + lr];
            #pragma unroll
            for (int i = 0; i < 4; i++)
                #pragma unroll
                for (int j = 0; j < 4; j++)
                    acc[i][j] = __builtin_amdgcn_mfma_f32_16x16x32_bf16(af[i], bfr[j], acc[i][j], 0, 0, 0);
        }
        __syncthreads();
    }

    #pragma unroll
    for (int i = 0; i < 4; i++)
        #pragma unroll
        for (int j = 0; j < 4; j++)
            #pragma unroll
            for (int r = 0; r < 4; r++) {
                int row = mBase + wr * 64 + i * 16 + quad * 4 + r;
                int col = nBase + wc * 64 + j * 16 + lr;
                float v = acc[i][j][r];
                size_t idx = (size_t)row * JS + col;
                __hip_bfloat16 h = __float2bfloat16(v);
                OutH[idx] = h;
                OutL[idx] = __float2bfloat16(v - __bfloat162float(h));
            }
}

// ---------------- head1 (split MFMA): gates = x1s @ w0T + w0_row0*xin + b0 ----------------
__global__ __launch_bounds__(256) void head1_mfma(
    const __hip_bfloat16* __restrict__ x1h, const __hip_bfloat16* __restrict__ x1l,
    const float* __restrict__ xin1,
    const __hip_bfloat16* __restrict__ Wh, const __hip_bfloat16* __restrict__ Wl,
    const float* __restrict__ w0, const float* __restrict__ b0,
    const float* __restrict__ state,
    __hip_bfloat16* __restrict__ xh, __hip_bfloat16* __restrict__ xl,
    __hip_bfloat16* __restrict__ u_buf)
{
    __shared__ __align__(16) __hip_bfloat16 XsH[8192];
    __shared__ __align__(16) __hip_bfloat16 XsL[8192];
    __shared__ __align__(16) __hip_bfloat16 WhS[8192];
    __shared__ __align__(16) __hip_bfloat16 WlS[8192];

    int n0 = blockIdx.x * 128;
    int b  = blockIdx.y;
    int tid = threadIdx.x;
    int wave = tid >> 6, lane = tid & 63;
    int quad = lane >> 4, lr = lane & 15;
    int wr = wave >> 1, wc = wave & 1;

    #pragma unroll
    for (int ch = 0; ch < 4; ch++) {
        int idx = (wave * 4 + ch) * 64 + lane;
        int c = idx >> 7, n = idx & 127;
        size_t gx = (size_t)(n0 + n) * JS + b * 64 + c * 8;
        gload_lds16(x1h + gx, XsH + (wave * 4 + ch) * 512);
        gload_lds16(x1l + gx, XsL + (wave * 4 + ch) * 512);
        gload_lds16(Wh + (size_t)idx * 8, WhS + (wave * 4 + ch) * 512);
        gload_lds16(Wl + (size_t)idx * 8, WlS + (wave * 4 + ch) * 512);
    }
    __syncthreads();

    f32x4 acc[4][4];
    #pragma unroll
    for (int i = 0; i < 4; i++)
        #pragma unroll
        for (int j = 0; j < 4; j++) { f32x4 z = {0.f,0.f,0.f,0.f}; acc[i][j] = z; }

    const s16x8* XhV = (const s16x8*)XsH;
    const s16x8* XlV = (const s16x8*)XsL;
    const s16x8* WhV = (const s16x8*)WhS;
    const s16x8* WlV = (const s16x8*)WlS;
    #pragma unroll
    for (int ks = 0; ks < 2; ks++) {
        int kb = ks * 4 + quad;
        s16x8 ah[4], al[4], bh[4], bl[4];
        #pragma unroll
        for (int i = 0; i < 4; i++) {
            int idx = kb * 128 + wr * 64 + i * 16 + lr;
            ah[i] = XhV[idx]; al[i] = XlV[idx];
        }
        #pragma unroll
        for (int j = 0; j < 4; j++) {
            int idx = kb * 128 + wc * 64 + j * 16 + lr;
            bh[j] = WhV[idx]; bl[j] = WlV[idx];
        }
        #pragma unroll
        for (int i = 0; i < 4; i++)
            #pragma unroll
            for (int j = 0; j < 4; j++) {
                acc[i][j] = __builtin_amdgcn_mfma_f32_16x16x32_bf16(ah[i], bh[j], acc[i][j], 0, 0, 0);
                acc[i][j] = __builtin_amdgcn_mfma_f32_16x16x32_bf16(ah[i], bl[j], acc[i][j], 0, 0, 0);
                acc[i][j] = __builtin_amdgcn_mfma_f32_16x16x32_bf16(al[i], bh[j], acc[i][j], 0, 0, 0);
            }
    }
    __syncthreads();

    __hip_bfloat16* trH = XsH;   // [64 o][128 n]
    __hip_bfloat16* trL = XsL;

    #pragma unroll
    for (int i = 0; i < 4; i++)
        #pragma unroll
        for (int j = 0; j < 4; j++)
            #pragma unroll
            for (int r = 0; r < 4; r++) {
                int n_loc = wr * 64 + i * 16 + quad * 4 + r;
                int o = wc * 64 + j * 16 + lr;
                float xin = xin1[(size_t)(n0 + n_loc) * 64 + b];
                float g = acc[i][j][r] + w0[o] * xin + b0[o];
                float sg = sigmoidf_(g);
                if (wc == 0) {
                    float sv = state[(size_t)b * NU + (size_t)(n0 + n_loc) * 64 + o];
                    float rs = sg * sv;
                    __hip_bfloat16 h = __float2bfloat16(rs);
                    trH[o * 128 + n_loc] = h;
                    trL[o * 128 + n_loc] = __float2bfloat16(rs - __bfloat162float(h));
                } else {
                    u_buf[(size_t)b * NU + (size_t)(n0 + n_loc) * 64 + (o - 64)] = __float2bfloat16(sg);
                }
            }
    __syncthreads();

    {
        int row = tid >> 2, seg = tid & 3;
        const uint4* sh = (const uint4*)(trH + row * 128 + seg * 32);
        const uint4* sl = (const uint4*)(trL + row * 128 + seg * 32);
        uint4* dh = (uint4*)(xh + (size_t)(b * 64 + row) * N_NODES + n0 + seg * 32);
        uint4* dl = (uint4*)(xl + (size_t)(b * 64 + row) * N_NODES + n0 + seg * 32);
        #pragma unroll
        for (int q = 0; q < 4; q++) { dh[q] = sh[q]; dl[q] = sl[q]; }
    }
}

// ---------------- head2 (split MFMA): out = u*s + (1-u)*tanh(x1s@w1T + w1_row0*xin + b1) ----------------
__global__ __launch_bounds__(256) void head2_mfma(
    const __hip_bfloat16* __restrict__ x1h, const __hip_bfloat16* __restrict__ x1l,
    const float* __restrict__ xin1,
    const __hip_bfloat16* __restrict__ Wh, const __hip_bfloat16* __restrict__ Wl,
    const float* __restrict__ w1, const float* __restrict__ b1,
    const float* __restrict__ state, const __hip_bfloat16* __restrict__ u_buf,
    float* __restrict__ out)
{
    __shared__ __align__(16) __hip_bfloat16 XsH[8192];
    __shared__ __align__(16) __hip_bfloat16 XsL[8192];
    __shared__ __align__(16) __hip_bfloat16 WhS[4096];
    __shared__ __align__(16) __hip_bfloat16 WlS[4096];

    int n0 = blockIdx.x * 128;
    int b  = blockIdx.y;
    int tid = threadIdx.x;
    int wave = tid >> 6, lane = tid & 63;
    int quad = lane >> 4, lr = lane & 15;

    #pragma unroll
    for (int ch = 0; ch < 4; ch++) {
        int idx = (wave * 4 + ch) * 64 + lane;
        int c = idx >> 7, n = idx & 127;
        size_t gx = (size_t)(n0 + n) * JS + b * 64 + c * 8;
        gload_lds16(x1h + gx, XsH + (wave * 4 + ch) * 512);
        gload_lds16(x1l + gx, XsL + (wave * 4 + ch) * 512);
    }
    #pragma unroll
    for (int ch = 0; ch < 2; ch++) {
        int idx = (wave * 2 + ch) * 64 + lane;
        gload_lds16(Wh + (size_t)idx * 8, WhS + (wave * 2 + ch) * 512);
        gload_lds16(Wl + (size_t)idx * 8, WlS + (wave * 2 + ch) * 512);
    }
    __syncthreads();

    f32x4 acc[2][4];
    #pragma unroll
    for (int i = 0; i < 2; i++)
        #pragma unroll
        for (int j = 0; j < 4; j++) { f32x4 z = {0.f,0.f,0.f,0.f}; acc[i][j] = z; }

    const s16x8* XhV = (const s16x8*)XsH;
    const s16x8* XlV = (const s16x8*)XsL;
    const s16x8* WhV = (const s16x8*)WhS;
    const s16x8* WlV = (const s16x8*)WlS;
    #pragma unroll
    for (int ks = 0; ks < 2; ks++) {
        int kb = ks * 4 + quad;
        s16x8 ah[2], al[2], bh[4], bl[4];
        #pragma unroll
        for (int i = 0; i < 2; i++) {
            int idx = kb * 128 + wave * 32 + i * 16 + lr;
            ah[i] = XhV[idx]; al[i] = XlV[idx];
        }
        #pragma unroll
        for (int j = 0; j < 4; j++) {
            int idx = kb * 64 + j * 16 + lr;
            bh[j] = WhV[idx]; bl[j] = WlV[idx];
        }
        #pragma unroll
        for (int i = 0; i < 2; i++)
            #pragma unroll
            for (int j = 0; j < 4; j++) {
                acc[i][j] = __builtin_amdgcn_mfma_f32_16x16x32_bf16(ah[i], bh[j], acc[i][j], 0, 0, 0);
                acc[i][j] = __builtin_amdgcn_mfma_f32_16x16x32_bf16(ah[i], bl[j], acc[i][j], 0, 0, 0);
                acc[i][j] = __builtin_amdgcn_mfma_f32_16x16x32_bf16(al[i], bh[j], acc[i][j], 0, 0, 0);
            }
    }

    #pragma unroll
    for (int i = 0; i < 2; i++)
        #pragma unroll
        for (int j = 0; j < 4; j++)
            #pragma unroll
            for (int r = 0; r < 4; r++) {
                int n_loc = wave * 32 + i * 16 + quad * 4 + r;
                int o = j * 16 + lr;
                float xin = xin1[(size_t)(n0 + n_loc) * 64 + b];
                float g = acc[i][j][r] + w1[o] * xin + b1[o];
                float c = tanhf(g);
                size_t sidx = (size_t)b * NU + (size_t)(n0 + n_loc) * 64 + o;
                float ug = __bfloat162float(u_buf[sidx]);
                float sv = state[sidx];
                out[sidx] = ug * sv + (1.0f - ug) * c;
            }
}

extern "C" void kernel_launch(void* const* d_in, const int* in_sizes, int n_in,
                              void* d_out, int out_size, void* d_ws, size_t ws_size,
                              hipStream_t stream)
{
    const float* inputs = (const float*)d_in[0];
    const float* state  = (const float*)d_in[1];
    const float* adj    = (const float*)d_in[2];
    // d_in[3] = adj1 : unused (discarded outfc path)
    const float* afc    = (const float*)d_in[4];   // [C][N]
    const float* afct   = (const float*)d_in[5];   // [N][C]
    const float* w0     = (const float*)d_in[6];
    const float* b0     = (const float*)d_in[7];
    const float* w1     = (const float*)d_in[8];
    const float* b1     = (const float*)d_in[9];
    // d_in[10..13]: unused

    float* out = (float*)d_out;

    char* p = (char*)d_ws;
    __hip_bfloat16* adj_b    = (__hip_bfloat16*)p; p += (size_t)N_NODES * N_NODES * 2;   // 8.39 MB
    __hip_bfloat16* afc_h    = (__hip_bfloat16*)p; p += (size_t)C_NODES * N_NODES * 2;
    __hip_bfloat16* afc_l    = (__hip_bfloat16*)p; p += (size_t)C_NODES * N_NODES * 2;
    __hip_bfloat16* afct_h   = (__hip_bfloat16*)p; p += (size_t)N_NODES * C_NODES * 2;
    __hip_bfloat16* afct_l   = (__hip_bfloat16*)p; p += (size_t)N_NODES * C_NODES * 2;
    __hip_bfloat16* w0T_h    = (__hip_bfloat16*)p; p += 8192 * 2;
    __hip_bfloat16* w0T_l    = (__hip_bfloat16*)p; p += 8192 * 2;
    __hip_bfloat16* w1T_h    = (__hip_bfloat16*)p; p += 4096 * 2;
    __hip_bfloat16* w1T_l    = (__hip_bfloat16*)p; p += 4096 * 2;
    __hip_bfloat16* x0sT_h   = (__hip_bfloat16*)p; p += (size_t)JS * N_NODES * 2;        // 16.78 MB
    __hip_bfloat16* x0sT_l   = (__hip_bfloat16*)p; p += (size_t)JS * N_NODES * 2;
    __hip_bfloat16* x0fcT_h  = (__hip_bfloat16*)p; p += (size_t)JS * C_NODES * 2;        // 2.10 MB
    __hip_bfloat16* x0fcT_l  = (__hip_bfloat16*)p; p += (size_t)JS * C_NODES * 2;
    __hip_bfloat16* x1s_h    = (__hip_bfloat16*)p; p += (size_t)N_NODES * JS * 2;        // 16.78 MB
    __hip_bfloat16* x1s_l    = (__hip_bfloat16*)p; p += (size_t)N_NODES * JS * 2;
    __hip_bfloat16* u_buf    = (__hip_bfloat16*)p; p += (size_t)BATCH * NU * 2;          // 16.78 MB
    float*          xin1     = (float*)p;          p += (size_t)N_NODES * 64 * 4;        // 0.52 MB
    float*          y_in     = (float*)p;          p += (size_t)C_NODES * 64 * 4;        // 64 KB
    float*          part     = (float*)p;          p += (size_t)2 * JS * C_NODES * 4;    // 8.39 MB
    // total ~104 MB

    dim3 blk(256);

    // ---- once: converts ----
    cvt_bf16 <<<1024, blk, 0, stream>>>(adj,  adj_b, N_NODES * N_NODES);
    cvt_split<<<256,  blk, 0, stream>>>(afc,  afc_h,  afc_l,  C_NODES * N_NODES);
    cvt_split<<<256,  blk, 0, stream>>>(afct, afct_h, afct_l, N_NODES * C_NODES);
    cvt_w    <<<32,   blk, 0, stream>>>(w0, w1, w0T_h, w0T_l, w1T_h, w1T_l);

    // ---- once: input-channel contribution (exact fp32) ----
    input_fc  <<<C_NODES, blk, 0, stream>>>(afc, inputs, y_in);
    input_node<<<N_NODES, blk, 0, stream>>>(adj, afct, inputs, y_in, xin1);

    // ---- pass 1 ----
    build_x0sT<<<dim3(32, 64), blk, 0, stream>>>(state, x0sT_h, x0sT_l);
    gemm1_split<<<dim3(4, 64, 2), blk, 0, stream>>>(x0sT_h, x0sT_l, afc_h, afc_l, part);
    reduce_split<<<1024, blk, 0, stream>>>(part, x0fcT_h, x0fcT_l, JS * C_NODES);
    gemm_fused<<<dim3(32, 16), blk, 0, stream>>>(afct_h, afct_l, x0fcT_h, x0fcT_l,
                                                 adj_b, x0sT_h, x1s_h, x1s_l);
    head1_mfma<<<dim3(16, 64), blk, 0, stream>>>(x1s_h, x1s_l, xin1, w0T_h, w0T_l, w0, b0,
                                                 state, x0sT_h, x0sT_l, u_buf);

    // ---- pass 2 (x0sT now holds r*state hi/lo, written by head1) ----
    gemm1_split<<<dim3(4, 64, 2), blk, 0, stream>>>(x0sT_h, x0sT_l, afc_h, afc_l, part);
    reduce_split<<<1024, blk, 0, stream>>>(part, x0fcT_h, x0fcT_l, JS * C_NODES);
    gemm_fused<<<dim3(32, 16), blk, 0, stream>>>(afct_h, afct_l, x0fcT_h, x0fcT_l,
                                                 adj_b, x0sT_h, x1s_h, x1s_l);
    head2_mfma<<<dim3(16, 64), blk, 0, stream>>>(x1s_h, x1s_l, xin1, w1T_h, w1T_l, w1, b1,
                                                 state, u_buf, out);
}

// Round 7
// 649.884 us; speedup vs baseline: 3.2249x; 1.0964x over previous
//
#include <hip/hip_runtime.h>
#include <hip/hip_bf16.h>
#include <math.h>

#define N_NODES 2048
#define C_NODES 256
#define BATCH   64
#define UNITS   64
#define JS      4096                // state-part columns: j = b*64+u
#define NX      4160                // + 64 input-channel columns
#define JSX     4224                // padded to 33 x 128 tiles
#define NU      131072              // N_NODES * UNITS

typedef short  s16x8 __attribute__((ext_vector_type(8)));   // 8 bf16 in 4 VGPRs
typedef float  f32x4 __attribute__((ext_vector_type(4)));

__device__ __forceinline__ float sigmoidf_(float x) { return 1.0f / (1.0f + __expf(-x)); }

__device__ __forceinline__ void gload_lds16(const void* g, void* l) {
    __builtin_amdgcn_global_load_lds(
        (const __attribute__((address_space(1))) void*)g,
        (__attribute__((address_space(3))) void*)l, 16, 0, 0);
}

// ---------------- converts ----------------
__global__ __launch_bounds__(256) void cvt_bf16(const float* __restrict__ s,
                                                __hip_bfloat16* __restrict__ d, int n)
{
    int stride = gridDim.x * 256;
    for (int i = blockIdx.x * 256 + threadIdx.x; i < n; i += stride)
        d[i] = __float2bfloat16(s[i]);
}

__global__ __launch_bounds__(256) void cvt_split(const float* __restrict__ s,
                                                 __hip_bfloat16* __restrict__ dh,
                                                 __hip_bfloat16* __restrict__ dl, int n)
{
    int stride = gridDim.x * 256;
    for (int i = blockIdx.x * 256 + threadIdx.x; i < n; i += stride) {
        float v = s[i];
        __hip_bfloat16 h = __float2bfloat16(v);
        dh[i] = h;
        dl[i] = __float2bfloat16(v - __bfloat162float(h));
    }
}

// w0[65][128], w1[65][64] -> blocked transposed bf16 h/l: cell (c*O+o), elem jj = w[(1+c*8+jj)*O + o]
__global__ __launch_bounds__(256) void cvt_w(const float* __restrict__ w0,
                                             const float* __restrict__ w1,
                                             __hip_bfloat16* __restrict__ w0h, __hip_bfloat16* __restrict__ w0l,
                                             __hip_bfloat16* __restrict__ w1h, __hip_bfloat16* __restrict__ w1l)
{
    int stride = gridDim.x * 256;
    for (int e = blockIdx.x * 256 + threadIdx.x; e < 8192 + 4096; e += stride) {
        if (e < 8192) {  // w0T: O=128
            int jj = e & 7, cell = e >> 3;
            int o = cell & 127, c = cell >> 7;
            float v = w0[(size_t)(1 + c * 8 + jj) * 128 + o];
            __hip_bfloat16 h = __float2bfloat16(v);
            w0h[e] = h; w0l[e] = __float2bfloat16(v - __bfloat162float(h));
        } else {         // w1T: O=64
            int e2 = e - 8192;
            int jj = e2 & 7, cell = e2 >> 3;
            int o = cell & 63, c = cell >> 6;
            float v = w1[(size_t)(1 + c * 8 + jj) * 64 + o];
            __hip_bfloat16 h = __float2bfloat16(v);
            w1h[e2] = h; w1l[e2] = __float2bfloat16(v - __bfloat162float(h));
        }
    }
}

// once: x0sT rows 4096..4159 = inputs (hi/lo); zero rows 4160..4223 of x0sT and x0fcT
__global__ __launch_bounds__(256) void setup_ext(
    const float* __restrict__ inputs,
    __hip_bfloat16* __restrict__ xh, __hip_bfloat16* __restrict__ xl,
    __hip_bfloat16* __restrict__ fh, __hip_bfloat16* __restrict__ fl)
{
    int blk = blockIdx.x;
    if (blk < 64) {
        int b = blk;
        for (int n = threadIdx.x; n < N_NODES; n += 256) {
            float v = inputs[(size_t)b * N_NODES + n];
            __hip_bfloat16 h = __float2bfloat16(v);
            size_t o = (size_t)(JS + b) * N_NODES + n;
            xh[o] = h;
            xl[o] = __float2bfloat16(v - __bfloat162float(h));
        }
    } else {
        int r = NX + (blk - 64);   // 4160..4223
        __hip_bfloat16 z = __float2bfloat16(0.0f);
        for (int n = threadIdx.x; n < N_NODES; n += 256) {
            size_t o = (size_t)r * N_NODES + n;
            xh[o] = z; xl[o] = z;
        }
        for (int c = threadIdx.x; c < C_NODES; c += 256) {
            size_t o = (size_t)r * C_NODES + c;
            fh[o] = z; fl[o] = z;
        }
    }
}

// pass-1 x0sT build: state[b][n*64+u] -> x0sT_h/l[(b*64+u)][n]
__global__ __launch_bounds__(256) void build_x0sT(const float* __restrict__ st,
                                                  __hip_bfloat16* __restrict__ xh,
                                                  __hip_bfloat16* __restrict__ xl)
{
    __shared__ float Ls[64 * 65];
    int n0 = blockIdx.x * 64;
    int b  = blockIdx.y;
    int t  = threadIdx.x;
    #pragma unroll
    for (int it = 0; it < 16; it++) {
        int idx = t + it * 256;
        int i = idx >> 6, u = idx & 63;
        Ls[i * 65 + u] = st[(size_t)b * NU + (size_t)(n0 + i) * 64 + u];
    }
    __syncthreads();
    #pragma unroll
    for (int it = 0; it < 16; it++) {
        int idx = t + it * 256;
        int u = idx >> 6, i = idx & 63;
        float v = Ls[i * 65 + u];
        __hip_bfloat16 h = __float2bfloat16(v);
        size_t o = (size_t)(b * 64 + u) * N_NODES + n0 + i;
        xh[o] = h;
        xl[o] = __float2bfloat16(v - __bfloat162float(h));
    }
}

// ---------------- GEMM1 (coarse, split-K): part[kp] = x0sT_ext @ afc^T ----------------
// Out[j][c], M=4160(j incl. input rows), N=256(c), K=2048; 64x64 tiles; 3-term split.
__global__ __launch_bounds__(256) void gemm1_split(
    const __hip_bfloat16* __restrict__ Ah, const __hip_bfloat16* __restrict__ Al,
    const __hip_bfloat16* __restrict__ Bh, const __hip_bfloat16* __restrict__ Bl,
    float* __restrict__ part)
{
    __shared__ __align__(16) __hip_bfloat16 AsH[4096];
    __shared__ __align__(16) __hip_bfloat16 AsL[4096];
    __shared__ __align__(16) __hip_bfloat16 BsH[4096];
    __shared__ __align__(16) __hip_bfloat16 BsL[4096];   // 32 KB total

    const int K = N_NODES;
    int tid  = threadIdx.x;
    int wave = tid >> 6, lane = tid & 63;
    int quad = lane >> 4, lr = lane & 15;
    int mBase = blockIdx.y * 64;     // j (0..4159)
    int nBase = blockIdx.x * 64;     // c
    int k0base = blockIdx.z * (K / 2);

    const __hip_bfloat16 *gAh[2], *gAl[2], *gBh[2], *gBl[2];
    __hip_bfloat16 *lAh[2], *lAl[2], *lBh[2], *lBl[2];
    #pragma unroll
    for (int ch = 0; ch < 2; ch++) {
        int cell = (wave * 2 + ch) * 64 + lane;
        int kb = cell >> 6, mm = cell & 63;
        size_t offA = (size_t)(mBase + mm) * K + k0base + kb * 8;
        size_t offB = (size_t)(nBase + mm) * K + k0base + kb * 8;
        gAh[ch] = Ah + offA; gAl[ch] = Al + offA;
        gBh[ch] = Bh + offB; gBl[ch] = Bl + offB;
        int lo = (wave * 2 + ch) * 512;
        lAh[ch] = AsH + lo; lAl[ch] = AsL + lo;
        lBh[ch] = BsH + lo; lBl[ch] = BsL + lo;
    }

    f32x4 acc[4];
    #pragma unroll
    for (int j = 0; j < 4; j++) { f32x4 z = {0.f,0.f,0.f,0.f}; acc[j] = z; }

    for (int k0 = 0; k0 < K / 2; k0 += 64) {
        #pragma unroll
        for (int ch = 0; ch < 2; ch++) {
            gload_lds16(gAh[ch] + k0, lAh[ch]);
            gload_lds16(gAl[ch] + k0, lAl[ch]);
            gload_lds16(gBh[ch] + k0, lBh[ch]);
            gload_lds16(gBl[ch] + k0, lBl[ch]);
        }
        __syncthreads();
        const s16x8* AhV = (const s16x8*)AsH;
        const s16x8* AlV = (const s16x8*)AsL;
        const s16x8* BhV = (const s16x8*)BsH;
        const s16x8* BlV = (const s16x8*)BsL;
        #pragma unroll
        for (int ks = 0; ks < 2; ks++) {
            int kb = ks * 4 + quad;
            s16x8 ah = AhV[kb * 64 + wave * 16 + lr];
            s16x8 al = AlV[kb * 64 + wave * 16 + lr];
            s16x8 bh[4], bl[4];
            #pragma unroll
            for (int j = 0; j < 4; j++) {
                bh[j] = BhV[kb * 64 + j * 16 + lr];
                bl[j] = BlV[kb * 64 + j * 16 + lr];
            }
            #pragma unroll
            for (int j = 0; j < 4; j++) {
                acc[j] = __builtin_amdgcn_mfma_f32_16x16x32_bf16(ah, bh[j], acc[j], 0, 0, 0);
                acc[j] = __builtin_amdgcn_mfma_f32_16x16x32_bf16(ah, bl[j], acc[j], 0, 0, 0);
                acc[j] = __builtin_amdgcn_mfma_f32_16x16x32_bf16(al, bh[j], acc[j], 0, 0, 0);
            }
        }
        __syncthreads();
    }

    float* dst = part + (size_t)blockIdx.z * NX * C_NODES;
    #pragma unroll
    for (int j = 0; j < 4; j++)
        #pragma unroll
        for (int r = 0; r < 4; r++) {
            int row = mBase + wave * 16 + quad * 4 + r;
            int col = nBase + j * 16 + lr;
            dst[(size_t)row * C_NODES + col] = acc[j][r];
        }
}

// reduce two split-K partials -> hi/lo bf16 pair
__global__ __launch_bounds__(256) void reduce_split(const float* __restrict__ part,
                                                    __hip_bfloat16* __restrict__ oh,
                                                    __hip_bfloat16* __restrict__ ol, int n)
{
    int stride = gridDim.x * 256;
    for (int i = blockIdx.x * 256 + threadIdx.x; i < n; i += stride) {
        float v = part[i] + part[(size_t)n + i];
        __hip_bfloat16 h = __float2bfloat16(v);
        oh[i] = h;
        ol[i] = __float2bfloat16(v - __bfloat162float(h));
    }
}

// ---------------- fused per-pass GEMM: x1 = adj@x0_ext + sigmoid(afct@x0fc_ext) ----------------
// Phase 1 (K=256, 3-term split): acc = afct @ x0fcT^T ; acc = sigmoid(acc)
// Phase 2 (K=2048, plain):       acc += adj @ x0sT^T
// M=2048(n) x N=4224(j: 4096 state + 64 input + 64 pad), 128x128 tiles, grid (33,16).
__global__ __launch_bounds__(256, 2) void gemm_fused(
    const __hip_bfloat16* __restrict__ Ah, const __hip_bfloat16* __restrict__ Al,  // afct h/l [2048][256]
    const __hip_bfloat16* __restrict__ Bh, const __hip_bfloat16* __restrict__ Bl,  // x0fcT h/l [4224][256]
    const __hip_bfloat16* __restrict__ A2, const __hip_bfloat16* __restrict__ B2,  // adj [2048][2048], x0sT_h [4224][2048]
    __hip_bfloat16* __restrict__ OutH, __hip_bfloat16* __restrict__ OutL)
{
    __shared__ __align__(16) __hip_bfloat16 S1[8192];
    __shared__ __align__(16) __hip_bfloat16 S2[8192];
    __shared__ __align__(16) __hip_bfloat16 S3[8192];
    __shared__ __align__(16) __hip_bfloat16 S4[8192];   // 64 KB

    int tid  = threadIdx.x;
    int wave = tid >> 6, lane = tid & 63;
    int quad = lane >> 4, lr = lane & 15;
    int wr = wave >> 1, wc = wave & 1;
    int mBase = blockIdx.y * 128, nBase = blockIdx.x * 128;

    int cellkb[4], cellmm[4];
    #pragma unroll
    for (int ch = 0; ch < 4; ch++) {
        int cell = (wave * 4 + ch) * 64 + lane;
        cellkb[ch] = cell >> 7;
        cellmm[ch] = cell & 127;
    }

    f32x4 acc[4][4];
    #pragma unroll
    for (int i = 0; i < 4; i++)
        #pragma unroll
        for (int j = 0; j < 4; j++) { f32x4 z = {0.f,0.f,0.f,0.f}; acc[i][j] = z; }

    // ---- phase 1: coarse, K=256, 3-term split ----
    for (int k0 = 0; k0 < C_NODES; k0 += 64) {
        #pragma unroll
        for (int ch = 0; ch < 4; ch++) {
            size_t offA = (size_t)(mBase + cellmm[ch]) * C_NODES + k0 + cellkb[ch] * 8;
            size_t offB = (size_t)(nBase + cellmm[ch]) * C_NODES + k0 + cellkb[ch] * 8;
            int lo = (wave * 4 + ch) * 512;
            gload_lds16(Ah + offA, S1 + lo);
            gload_lds16(Al + offA, S2 + lo);
            gload_lds16(Bh + offB, S3 + lo);
            gload_lds16(Bl + offB, S4 + lo);
        }
        __syncthreads();
        const s16x8* AhV = (const s16x8*)S1;
        const s16x8* AlV = (const s16x8*)S2;
        const s16x8* BhV = (const s16x8*)S3;
        const s16x8* BlV = (const s16x8*)S4;
        #pragma unroll
        for (int ks = 0; ks < 2; ks++) {
            int kb = ks * 4 + quad;
            s16x8 ah[4], al[4], bh[4], bl[4];
            #pragma unroll
            for (int i = 0; i < 4; i++) {
                int idx = kb * 128 + wr * 64 + i * 16 + lr;
                ah[i] = AhV[idx]; al[i] = AlV[idx];
            }
            #pragma unroll
            for (int j = 0; j < 4; j++) {
                int idx = kb * 128 + wc * 64 + j * 16 + lr;
                bh[j] = BhV[idx]; bl[j] = BlV[idx];
            }
            #pragma unroll
            for (int i = 0; i < 4; i++)
                #pragma unroll
                for (int j = 0; j < 4; j++) {
                    acc[i][j] = __builtin_amdgcn_mfma_f32_16x16x32_bf16(ah[i], bh[j], acc[i][j], 0, 0, 0);
                    acc[i][j] = __builtin_amdgcn_mfma_f32_16x16x32_bf16(ah[i], bl[j], acc[i][j], 0, 0, 0);
                    acc[i][j] = __builtin_amdgcn_mfma_f32_16x16x32_bf16(al[i], bh[j], acc[i][j], 0, 0, 0);
                }
        }
        __syncthreads();
    }

    #pragma unroll
    for (int i = 0; i < 4; i++)
        #pragma unroll
        for (int j = 0; j < 4; j++)
            #pragma unroll
            for (int r = 0; r < 4; r++)
                acc[i][j][r] = sigmoidf_(acc[i][j][r]);

    // ---- phase 2: adj, K=2048, plain bf16 ----
    for (int k0 = 0; k0 < N_NODES; k0 += 64) {
        #pragma unroll
        for (int ch = 0; ch < 4; ch++) {
            size_t offA = (size_t)(mBase + cellmm[ch]) * N_NODES + k0 + cellkb[ch] * 8;
            size_t offB = (size_t)(nBase + cellmm[ch]) * N_NODES + k0 + cellkb[ch] * 8;
            int lo = (wave * 4 + ch) * 512;
            gload_lds16(A2 + offA, S1 + lo);
            gload_lds16(B2 + offB, S3 + lo);
        }
        __syncthreads();
        const s16x8* AsV = (const s16x8*)S1;
        const s16x8* BsV = (const s16x8*)S3;
        #pragma unroll
        for (int ks = 0; ks < 2; ks++) {
            int kb = ks * 4 + quad;
            s16x8 af[4], bfr[4];
            #pragma unroll
            for (int i = 0; i < 4; i++) af[i]  = AsV[kb * 128 + wr * 64 + i * 16 + lr];
            #pragma unroll
            for (int j = 0; j < 4; j++) bfr[j] = BsV[kb * 128 + wc * 64 + j * 16 + lr];
            #pragma unroll
            for (int i = 0; i < 4; i++)
                #pragma unroll
                for (int j = 0; j < 4; j++)
                    acc[i][j] = __builtin_amdgcn_mfma_f32_16x16x32_bf16(af[i], bfr[j], acc[i][j], 0, 0, 0);
        }
        __syncthreads();
    }

    #pragma unroll
    for (int i = 0; i < 4; i++)
        #pragma unroll
        for (int j = 0; j < 4; j++)
            #pragma unroll
            for (int r = 0; r < 4; r++) {
                int row = mBase + wr * 64 + i * 16 + quad * 4 + r;
                int col = nBase + wc * 64 + j * 16 + lr;
                float v = acc[i][j][r];
                size_t idx = (size_t)row * JSX + col;
                __hip_bfloat16 h = __float2bfloat16(v);
                OutH[idx] = h;
                OutL[idx] = __float2bfloat16(v - __bfloat162float(h));
            }
}

// ---------------- head1 (split MFMA): gates = x1s @ w0T + w0_row0*xin + b0 ----------------
__global__ __launch_bounds__(256) void head1_mfma(
    const __hip_bfloat16* __restrict__ x1h, const __hip_bfloat16* __restrict__ x1l,
    const __hip_bfloat16* __restrict__ Wh, const __hip_bfloat16* __restrict__ Wl,
    const float* __restrict__ w0, const float* __restrict__ b0,
    const float* __restrict__ state,
    __hip_bfloat16* __restrict__ xh, __hip_bfloat16* __restrict__ xl,
    __hip_bfloat16* __restrict__ u_buf)
{
    __shared__ __align__(16) __hip_bfloat16 XsH[8192];
    __shared__ __align__(16) __hip_bfloat16 XsL[8192];
    __shared__ __align__(16) __hip_bfloat16 WhS[8192];
    __shared__ __align__(16) __hip_bfloat16 WlS[8192];
    __shared__ float xinS[128];

    int n0 = blockIdx.x * 128;
    int b  = blockIdx.y;
    int tid = threadIdx.x;
    int wave = tid >> 6, lane = tid & 63;
    int quad = lane >> 4, lr = lane & 15;
    int wr = wave >> 1, wc = wave & 1;

    #pragma unroll
    for (int ch = 0; ch < 4; ch++) {
        int idx = (wave * 4 + ch) * 64 + lane;
        int c = idx >> 7, n = idx & 127;
        size_t gx = (size_t)(n0 + n) * JSX + b * 64 + c * 8;
        gload_lds16(x1h + gx, XsH + (wave * 4 + ch) * 512);
        gload_lds16(x1l + gx, XsL + (wave * 4 + ch) * 512);
        gload_lds16(Wh + (size_t)idx * 8, WhS + (wave * 4 + ch) * 512);
        gload_lds16(Wl + (size_t)idx * 8, WlS + (wave * 4 + ch) * 512);
    }
    if (tid < 128) {
        size_t o = (size_t)(n0 + tid) * JSX + JS + b;
        xinS[tid] = __bfloat162float(x1h[o]) + __bfloat162float(x1l[o]);
    }
    __syncthreads();

    f32x4 acc[4][4];
    #pragma unroll
    for (int i = 0; i < 4; i++)
        #pragma unroll
        for (int j = 0; j < 4; j++) { f32x4 z = {0.f,0.f,0.f,0.f}; acc[i][j] = z; }

    const s16x8* XhV = (const s16x8*)XsH;
    const s16x8* XlV = (const s16x8*)XsL;
    const s16x8* WhV = (const s16x8*)WhS;
    const s16x8* WlV = (const s16x8*)WlS;
    #pragma unroll
    for (int ks = 0; ks < 2; ks++) {
        int kb = ks * 4 + quad;
        s16x8 ah[4], al[4], bh[4], bl[4];
        #pragma unroll
        for (int i = 0; i < 4; i++) {
            int idx = kb * 128 + wr * 64 + i * 16 + lr;
            ah[i] = XhV[idx]; al[i] = XlV[idx];
        }
        #pragma unroll
        for (int j = 0; j < 4; j++) {
            int idx = kb * 128 + wc * 64 + j * 16 + lr;
            bh[j] = WhV[idx]; bl[j] = WlV[idx];
        }
        #pragma unroll
        for (int i = 0; i < 4; i++)
            #pragma unroll
            for (int j = 0; j < 4; j++) {
                acc[i][j] = __builtin_amdgcn_mfma_f32_16x16x32_bf16(ah[i], bh[j], acc[i][j], 0, 0, 0);
                acc[i][j] = __builtin_amdgcn_mfma_f32_16x16x32_bf16(ah[i], bl[j], acc[i][j], 0, 0, 0);
                acc[i][j] = __builtin_amdgcn_mfma_f32_16x16x32_bf16(al[i], bh[j], acc[i][j], 0, 0, 0);
            }
    }
    __syncthreads();

    __hip_bfloat16* trH = XsH;   // [64 o][128 n]
    __hip_bfloat16* trL = XsL;

    #pragma unroll
    for (int i = 0; i < 4; i++)
        #pragma unroll
        for (int j = 0; j < 4; j++)
            #pragma unroll
            for (int r = 0; r < 4; r++) {
                int n_loc = wr * 64 + i * 16 + quad * 4 + r;
                int o = wc * 64 + j * 16 + lr;
                float g = acc[i][j][r] + w0[o] * xinS[n_loc] + b0[o];
                float sg = sigmoidf_(g);
                if (wc == 0) {
                    float sv = state[(size_t)b * NU + (size_t)(n0 + n_loc) * 64 + o];
                    float rs = sg * sv;
                    __hip_bfloat16 h = __float2bfloat16(rs);
                    trH[o * 128 + n_loc] = h;
                    trL[o * 128 + n_loc] = __float2bfloat16(rs - __bfloat162float(h));
                } else {
                    u_buf[(size_t)b * NU + (size_t)(n0 + n_loc) * 64 + (o - 64)] = __float2bfloat16(sg);
                }
            }
    __syncthreads();

    {
        int row = tid >> 2, seg = tid & 3;
        const uint4* sh = (const uint4*)(trH + row * 128 + seg * 32);
        const uint4* sl = (const uint4*)(trL + row * 128 + seg * 32);
        uint4* dh = (uint4*)(xh + (size_t)(b * 64 + row) * N_NODES + n0 + seg * 32);
        uint4* dl = (uint4*)(xl + (size_t)(b * 64 + row) * N_NODES + n0 + seg * 32);
        #pragma unroll
        for (int q = 0; q < 4; q++) { dh[q] = sh[q]; dl[q] = sl[q]; }
    }
}

// ---------------- head2 (split MFMA): out = u*s + (1-u)*tanh(x1s@w1T + w1_row0*xin + b1) ----------------
__global__ __launch_bounds__(256) void head2_mfma(
    const __hip_bfloat16* __restrict__ x1h, const __hip_bfloat16* __restrict__ x1l,
    const __hip_bfloat16* __restrict__ Wh, const __hip_bfloat16* __restrict__ Wl,
    const float* __restrict__ w1, const float* __restrict__ b1,
    const float* __restrict__ state, const __hip_bfloat16* __restrict__ u_buf,
    float* __restrict__ out)
{
    __shared__ __align__(16) __hip_bfloat16 XsH[8192];
    __shared__ __align__(16) __hip_bfloat16 XsL[8192];
    __shared__ __align__(16) __hip_bfloat16 WhS[4096];
    __shared__ __align__(16) __hip_bfloat16 WlS[4096];
    __shared__ float xinS[128];

    int n0 = blockIdx.x * 128;
    int b  = blockIdx.y;
    int tid = threadIdx.x;
    int wave = tid >> 6, lane = tid & 63;
    int quad = lane >> 4, lr = lane & 15;

    #pragma unroll
    for (int ch = 0; ch < 4; ch++) {
        int idx = (wave * 4 + ch) * 64 + lane;
        int c = idx >> 7, n = idx & 127;
        size_t gx = (size_t)(n0 + n) * JSX + b * 64 + c * 8;
        gload_lds16(x1h + gx, XsH + (wave * 4 + ch) * 512);
        gload_lds16(x1l + gx, XsL + (wave * 4 + ch) * 512);
    }
    #pragma unroll
    for (int ch = 0; ch < 2; ch++) {
        int idx = (wave * 2 + ch) * 64 + lane;
        gload_lds16(Wh + (size_t)idx * 8, WhS + (wave * 2 + ch) * 512);
        gload_lds16(Wl + (size_t)idx * 8, WlS + (wave * 2 + ch) * 512);
    }
    if (tid < 128) {
        size_t o = (size_t)(n0 + tid) * JSX + JS + b;
        xinS[tid] = __bfloat162float(x1h[o]) + __bfloat162float(x1l[o]);
    }
    __syncthreads();

    f32x4 acc[2][4];
    #pragma unroll
    for (int i = 0; i < 2; i++)
        #pragma unroll
        for (int j = 0; j < 4; j++) { f32x4 z = {0.f,0.f,0.f,0.f}; acc[i][j] = z; }

    const s16x8* XhV = (const s16x8*)XsH;
    const s16x8* XlV = (const s16x8*)XsL;
    const s16x8* WhV = (const s16x8*)WhS;
    const s16x8* WlV = (const s16x8*)WlS;
    #pragma unroll
    for (int ks = 0; ks < 2; ks++) {
        int kb = ks * 4 + quad;
        s16x8 ah[2], al[2], bh[4], bl[4];
        #pragma unroll
        for (int i = 0; i < 2; i++) {
            int idx = kb * 128 + wave * 32 + i * 16 + lr;
            ah[i] = XhV[idx]; al[i] = XlV[idx];
        }
        #pragma unroll
        for (int j = 0; j < 4; j++) {
            int idx = kb * 64 + j * 16 + lr;
            bh[j] = WhV[idx]; bl[j] = WlV[idx];
        }
        #pragma unroll
        for (int i = 0; i < 2; i++)
            #pragma unroll
            for (int j = 0; j < 4; j++) {
                acc[i][j] = __builtin_amdgcn_mfma_f32_16x16x32_bf16(ah[i], bh[j], acc[i][j], 0, 0, 0);
                acc[i][j] = __builtin_amdgcn_mfma_f32_16x16x32_bf16(ah[i], bl[j], acc[i][j], 0, 0, 0);
                acc[i][j] = __builtin_amdgcn_mfma_f32_16x16x32_bf16(al[i], bh[j], acc[i][j], 0, 0, 0);
            }
    }

    #pragma unroll
    for (int i = 0; i < 2; i++)
        #pragma unroll
        for (int j = 0; j < 4; j++)
            #pragma unroll
            for (int r = 0; r < 4; r++) {
                int n_loc = wave * 32 + i * 16 + quad * 4 + r;
                int o = j * 16 + lr;
                float g = acc[i][j][r] + w1[o] * xinS[n_loc] + b1[o];
                float c = tanhf(g);
                size_t sidx = (size_t)b * NU + (size_t)(n0 + n_loc) * 64 + o;
                float ug = __bfloat162float(u_buf[sidx]);
                float sv = state[sidx];
                out[sidx] = ug * sv + (1.0f - ug) * c;
            }
}

extern "C" void kernel_launch(void* const* d_in, const int* in_sizes, int n_in,
                              void* d_out, int out_size, void* d_ws, size_t ws_size,
                              hipStream_t stream)
{
    const float* inputs = (const float*)d_in[0];
    const float* state  = (const float*)d_in[1];
    const float* adj    = (const float*)d_in[2];
    // d_in[3] = adj1 : unused (discarded outfc path)
    const float* afc    = (const float*)d_in[4];   // [C][N]
    const float* afct   = (const float*)d_in[5];   // [N][C]
    const float* w0     = (const float*)d_in[6];
    const float* b0     = (const float*)d_in[7];
    const float* w1     = (const float*)d_in[8];
    const float* b1     = (const float*)d_in[9];
    // d_in[10..13]: unused

    float* out = (float*)d_out;

    char* p = (char*)d_ws;
    __hip_bfloat16* adj_b    = (__hip_bfloat16*)p; p += (size_t)N_NODES * N_NODES * 2;   // 8.39 MB
    __hip_bfloat16* afc_h    = (__hip_bfloat16*)p; p += (size_t)C_NODES * N_NODES * 2;
    __hip_bfloat16* afc_l    = (__hip_bfloat16*)p; p += (size_t)C_NODES * N_NODES * 2;
    __hip_bfloat16* afct_h   = (__hip_bfloat16*)p; p += (size_t)N_NODES * C_NODES * 2;
    __hip_bfloat16* afct_l   = (__hip_bfloat16*)p; p += (size_t)N_NODES * C_NODES * 2;
    __hip_bfloat16* w0T_h    = (__hip_bfloat16*)p; p += 8192 * 2;
    __hip_bfloat16* w0T_l    = (__hip_bfloat16*)p; p += 8192 * 2;
    __hip_bfloat16* w1T_h    = (__hip_bfloat16*)p; p += 4096 * 2;
    __hip_bfloat16* w1T_l    = (__hip_bfloat16*)p; p += 4096 * 2;
    __hip_bfloat16* x0sT_h   = (__hip_bfloat16*)p; p += (size_t)JSX * N_NODES * 2;       // 17.3 MB
    __hip_bfloat16* x0sT_l   = (__hip_bfloat16*)p; p += (size_t)JSX * N_NODES * 2;
    __hip_bfloat16* x0fcT_h  = (__hip_bfloat16*)p; p += (size_t)JSX * C_NODES * 2;       // 2.16 MB
    __hip_bfloat16* x0fcT_l  = (__hip_bfloat16*)p; p += (size_t)JSX * C_NODES * 2;
    __hip_bfloat16* x1s_h    = (__hip_bfloat16*)p; p += (size_t)N_NODES * JSX * 2;       // 17.3 MB
    __hip_bfloat16* x1s_l    = (__hip_bfloat16*)p; p += (size_t)N_NODES * JSX * 2;
    __hip_bfloat16* u_buf    = (__hip_bfloat16*)p; p += (size_t)BATCH * NU * 2;          // 16.78 MB
    float*          part     = (float*)p;          p += (size_t)2 * NX * C_NODES * 4;    // 8.52 MB
    // total ~112 MB

    dim3 blk(256);

    // ---- once: converts + extended-row setup ----
    cvt_bf16 <<<1024, blk, 0, stream>>>(adj,  adj_b, N_NODES * N_NODES);
    cvt_split<<<256,  blk, 0, stream>>>(afc,  afc_h,  afc_l,  C_NODES * N_NODES);
    cvt_split<<<256,  blk, 0, stream>>>(afct, afct_h, afct_l, N_NODES * C_NODES);
    cvt_w    <<<32,   blk, 0, stream>>>(w0, w1, w0T_h, w0T_l, w1T_h, w1T_l);
    setup_ext<<<128,  blk, 0, stream>>>(inputs, x0sT_h, x0sT_l, x0fcT_h, x0fcT_l);

    // ---- pass 1 ----
    build_x0sT<<<dim3(32, 64), blk, 0, stream>>>(state, x0sT_h, x0sT_l);
    gemm1_split<<<dim3(4, 65, 2), blk, 0, stream>>>(x0sT_h, x0sT_l, afc_h, afc_l, part);
    reduce_split<<<1024, blk, 0, stream>>>(part, x0fcT_h, x0fcT_l, NX * C_NODES);
    gemm_fused<<<dim3(33, 16), blk, 0, stream>>>(afct_h, afct_l, x0fcT_h, x0fcT_l,
                                                 adj_b, x0sT_h, x1s_h, x1s_l);
    head1_mfma<<<dim3(16, 64), blk, 0, stream>>>(x1s_h, x1s_l, w0T_h, w0T_l, w0, b0,
                                                 state, x0sT_h, x0sT_l, u_buf);

    // ---- pass 2 (x0sT state rows now hold r*state hi/lo; input rows unchanged) ----
    gemm1_split<<<dim3(4, 65, 2), blk, 0, stream>>>(x0sT_h, x0sT_l, afc_h, afc_l, part);
    reduce_split<<<1024, blk, 0, stream>>>(part, x0fcT_h, x0fcT_l, NX * C_NODES);
    gemm_fused<<<dim3(33, 16), blk, 0, stream>>>(afct_h, afct_l, x0fcT_h, x0fcT_l,
                                                 adj_b, x0sT_h, x1s_h, x1s_l);
    head2_mfma<<<dim3(16, 64), blk, 0, stream>>>(x1s_h, x1s_l, w1T_h, w1T_l, w1, b1,
                                                 state, u_buf, out);
}